// Round 15
// baseline (150.860 us; speedup 1.0000x reference)
//
#include <hip/hip_runtime.h>
#include <hip/hip_bf16.h>
#include <stdint.h>

#define D_MODEL 1024
#define TOKENS  2048
#define HEADS   16
#define HDIM    64
#define NQKV    3072      // 3*D_MODEL
#define MROWS   4096      // BATCH*TOKENS
#define SCALE   0.18033688011112042f   // 0.125 * log2(e)

typedef __attribute__((ext_vector_type(4)))  float f32x4;
typedef __attribute__((ext_vector_type(16))) float f32x16;
typedef __attribute__((ext_vector_type(8)))  short bf16x8;

__device__ __forceinline__ unsigned short f2bf(float f) {
  union { float f; unsigned u; } v; v.f = f;
  unsigned u = v.u + 0x7FFFu + ((v.u >> 16) & 1u);   // RNE
  return (unsigned short)(u >> 16);
}
__device__ __forceinline__ float bf2f(unsigned short b) {
  union { unsigned u; float f; } v; v.u = ((unsigned)b) << 16;
  return v.f;
}
__device__ __forceinline__ unsigned cvt_pk_bf16(float lo, float hi) {
  unsigned r;
  asm("v_cvt_pk_bf16_f32 %0, %1, %2" : "=v"(r) : "v"(lo), "v"(hi));
  return r;
}
__device__ __forceinline__ float xchg32(float v) {
  return __shfl_xor(v, 32);
}
__device__ __forceinline__ bf16x8 pfrag8(const float* g) {
  union { uint4 u; bf16x8 v; } r;
  r.u.x = cvt_pk_bf16(g[0], g[1]);
  r.u.y = cvt_pk_bf16(g[2], g[3]);
  r.u.z = cvt_pk_bf16(g[4], g[5]);
  r.u.w = cvt_pk_bf16(g[6], g[7]);
  return r.v;
}
__device__ __forceinline__ float max32t(const f32x16& a, const f32x16& b) {
  float t[16];
#pragma unroll
  for (int r = 0; r < 16; ++r) t[r] = fmaxf(a[r], b[r]);
#pragma unroll
  for (int s = 8; s > 0; s >>= 1)
#pragma unroll
    for (int r = 0; r < s; ++r) t[r] = fmaxf(t[r], t[r + s]);
  return t[0];
}
__device__ __forceinline__ float sum32t(const float* a, const float* b) {
  float t[16];
#pragma unroll
  for (int r = 0; r < 16; ++r) t[r] = a[r] + b[r];
#pragma unroll
  for (int s = 8; s > 0; s >>= 1)
#pragma unroll
    for (int r = 0; r < s; ++r) t[r] = t[r] + t[r + s];
  return t[0];
}

#define GLOAD16(g, l)                                                          \
  __builtin_amdgcn_global_load_lds(                                            \
      (const __attribute__((address_space(1))) unsigned int*)(g),              \
      (__attribute__((address_space(3))) unsigned int*)(l), 16, 0, 0)

// ---------------------------------------------------------------------------
// fp32 -> bf16 convert pass (X then W, contiguous).
// ---------------------------------------------------------------------------
__global__ __launch_bounds__(256) void cvt_bf16(const float* __restrict__ X,
                                                const float* __restrict__ W,
                                                unsigned short* __restrict__ Xb,
                                                unsigned short* __restrict__ Wb) {
  const size_t NX = (size_t)MROWS * D_MODEL;
  size_t i = ((size_t)blockIdx.x * 256 + threadIdx.x) * 8;
  const float* src; unsigned short* dst; size_t off;
  if (i < NX) { src = X; dst = Xb; off = i; }
  else        { src = W; dst = Wb; off = i - NX; }
  float4 a = ((const float4*)(src + off))[0];
  float4 b = ((const float4*)(src + off))[1];
  union { unsigned short s[8]; uint4 v; } u;
  u.s[0] = f2bf(a.x); u.s[1] = f2bf(a.y); u.s[2] = f2bf(a.z); u.s[3] = f2bf(a.w);
  u.s[4] = f2bf(b.x); u.s[5] = f2bf(b.y); u.s[6] = f2bf(b.z); u.s[7] = f2bf(b.w);
  *(uint4*)(dst + off) = u.v;
}

// ---------------------------------------------------------------------------
// 8-phase 256x256 GEMM. Full (row&7)<<4 XOR swizzle (8-slot spread -> 2
// lanes/bank free) on both staging source and fragment reads.
// ---------------------------------------------------------------------------
__global__ __launch_bounds__(512, 1) void gemm8(const unsigned short* __restrict__ A,
                                                const unsigned short* __restrict__ B,
                                                unsigned short* __restrict__ C) {
  __shared__ unsigned short sA[2][2][128][64];
  __shared__ unsigned short sB[2][2][128][64];

  const int tid  = threadIdx.x;
  const int lane = tid & 63;
  const int wave = tid >> 6;
  const int wr   = wave >> 2;
  const int wc   = wave & 3;
  const int l15  = lane & 15;
  const int lg   = lane >> 4;

  const int bm = blockIdx.x;
  const int bn = blockIdx.y;

  f32x4 acc[8][4];
#pragma unroll
  for (int i = 0; i < 8; ++i)
#pragma unroll
    for (int j = 0; j < 4; ++j)
#pragma unroll
      for (int r = 0; r < 4; ++r) acc[i][j][r] = 0.f;

  const int srow = tid >> 3;
  const int scb  = (tid & 7) * 16;
  const int ssce = (scb ^ ((srow & 7) << 4)) >> 1;

  const unsigned short* Ag = A + (size_t)(bm * 256) * D_MODEL;
  const unsigned short* Bg = B + (size_t)(bn * 256) * D_MODEL;

#define STG_A(buf, hf, t)                                                      \
  { GLOAD16(Ag + (size_t)((hf) * 128 + srow) * D_MODEL + (t) * 64 + ssce,      \
            (char*)&sA[buf][hf][0][0] + srow * 128 + scb);                     \
    GLOAD16(Ag + (size_t)((hf) * 128 + 64 + srow) * D_MODEL + (t) * 64 + ssce, \
            (char*)&sA[buf][hf][0][0] + 8192 + srow * 128 + scb); }
#define STG_B(buf, hf, t)                                                      \
  { GLOAD16(Bg + (size_t)((hf) * 128 + srow) * D_MODEL + (t) * 64 + ssce,      \
            (char*)&sB[buf][hf][0][0] + srow * 128 + scb);                     \
    GLOAD16(Bg + (size_t)((hf) * 128 + 64 + srow) * D_MODEL + (t) * 64 + ssce, \
            (char*)&sB[buf][hf][0][0] + 8192 + srow * 128 + scb); }

  const char* aBse[2] = { (const char*)&sA[0][wr][0][0], (const char*)&sA[1][wr][0][0] };
  const char* bBse[2] = { (const char*)&sB[0][wc >> 1][0][0], (const char*)&sB[1][wc >> 1][0][0] };
  const int swzl = (l15 & 7) << 4;
  const int cbs0 = (lg * 16) ^ swzl;
  const int cbs1 = (64 + lg * 16) ^ swzl;
  const int arow = l15 * 128;
  const int brow = ((wc & 1) * 64 + l15) * 128;

#define DO_PHASE(qm, qn, buf, STAGE_STMT, DO_VM)                               \
  {                                                                            \
    bf16x8 a_[4][2], b_[2][2];                                                 \
    _Pragma("unroll")                                                          \
    for (int i = 0; i < 4; ++i) {                                              \
      a_[i][0] = *(const bf16x8*)(aBse[buf] + ((qm)*4 + i) * 2048 + arow + cbs0); \
      a_[i][1] = *(const bf16x8*)(aBse[buf] + ((qm)*4 + i) * 2048 + arow + cbs1); \
    }                                                                          \
    _Pragma("unroll")                                                          \
    for (int n = 0; n < 2; ++n) {                                              \
      b_[n][0] = *(const bf16x8*)(bBse[buf] + ((qn)*2 + n) * 2048 + brow + cbs0); \
      b_[n][1] = *(const bf16x8*)(bBse[buf] + ((qn)*2 + n) * 2048 + brow + cbs1); \
    }                                                                          \
    STAGE_STMT;                                                                \
    if (DO_VM) asm volatile("s_waitcnt vmcnt(2)" ::: "memory");                \
    __builtin_amdgcn_s_barrier();                                              \
    asm volatile("s_waitcnt lgkmcnt(0)" ::: "memory");                         \
    __builtin_amdgcn_sched_barrier(0);                                         \
    __builtin_amdgcn_s_setprio(1);                                             \
    _Pragma("unroll")                                                          \
    for (int ks = 0; ks < 2; ++ks)                                             \
      _Pragma("unroll")                                                        \
      for (int i = 0; i < 4; ++i)                                              \
        _Pragma("unroll")                                                      \
        for (int n = 0; n < 2; ++n)                                            \
          acc[(qm)*4 + i][(qn)*2 + n] = __builtin_amdgcn_mfma_f32_16x16x32_bf16( \
              a_[i][ks], b_[n][ks], acc[(qm)*4 + i][(qn)*2 + n], 0, 0, 0);     \
    __builtin_amdgcn_s_setprio(0);                                             \
    __builtin_amdgcn_s_barrier();                                              \
  }

  STG_A(0, 0, 0);
  STG_B(0, 0, 0);
  STG_A(0, 1, 0);
  STG_B(0, 1, 0);
  STG_B(1, 0, 1);
  asm volatile("s_waitcnt vmcnt(2)" ::: "memory");
  __builtin_amdgcn_s_barrier();

#pragma unroll 1
  for (int j = 0; j < 8; ++j) {
    const int t1 = 2 * j + 1;
    const int t2 = 2 * j + 2;
    const int t3 = 2 * j + 3;
    DO_PHASE(0, 0, 0, { STG_A(1, 0, t1); }, 0);
    DO_PHASE(1, 0, 0, { STG_A(1, 1, t1); }, 0);
    DO_PHASE(0, 1, 0, { STG_B(1, 1, t1); }, 0);
    DO_PHASE(1, 1, 0, { if (t2 < 16) STG_B(0, 0, t2); }, 1);
    DO_PHASE(0, 0, 1, { if (t2 < 16) STG_A(0, 0, t2); }, 0);
    DO_PHASE(1, 0, 1, { if (t2 < 16) STG_A(0, 1, t2); }, 0);
    DO_PHASE(0, 1, 1, { if (t2 < 16) STG_B(0, 1, t2); }, 0);
    DO_PHASE(1, 1, 1, { if (t3 < 16) STG_B(1, 0, t3); }, 1);
  }

  const int orow0 = bm * 256 + wr * 128 + lg * 4;
  const int ocol0 = bn * 256 + wc * 64 + l15;
#pragma unroll
  for (int mi = 0; mi < 8; ++mi)
#pragma unroll
    for (int ni = 0; ni < 4; ++ni)
#pragma unroll
      for (int r = 0; r < 4; ++r)
        C[(size_t)(orow0 + mi * 16 + r) * NQKV + ocol0 + ni * 16] = f2bf(acc[mi][ni][r]);
#undef STG_A
#undef STG_B
#undef DO_PHASE
}

// ---------------------------------------------------------------------------
// Fallback fp32-input GEMM for small ws (round-1 verified).
// ---------------------------------------------------------------------------
__global__ __launch_bounds__(256) void qkv_gemm(const float* __restrict__ X,
                                                const float* __restrict__ W,
                                                unsigned short* __restrict__ QKV) {
  __shared__ unsigned short sA[128 * 32];
  __shared__ unsigned short sB[128 * 32];
  const int tid  = threadIdx.x;
  const int lane = tid & 63;
  const int wave = tid >> 6;
  const int wr = wave >> 1, wc = wave & 1;
  const int row0 = blockIdx.x * 128;
  const int col0 = blockIdx.y * 128;

  f32x4 acc[4][4];
#pragma unroll
  for (int i = 0; i < 4; ++i)
#pragma unroll
    for (int j = 0; j < 4; ++j)
#pragma unroll
      for (int r = 0; r < 4; ++r) acc[i][j][r] = 0.f;

  const int srow = tid >> 1;
  const int scol = (tid & 1) * 16;
  union U16 { unsigned short s[8]; uint4 v; };

#pragma unroll 1
  for (int k0 = 0; k0 < D_MODEL; k0 += 32) {
    {
      const float* ga = X + (size_t)(row0 + srow) * D_MODEL + k0 + scol;
      const float* gb = W + (size_t)(col0 + srow) * D_MODEL + k0 + scol;
      float va[16], vb[16];
#pragma unroll
      for (int i = 0; i < 4; ++i) {
        float4 t = ((const float4*)ga)[i];
        va[4*i+0] = t.x; va[4*i+1] = t.y; va[4*i+2] = t.z; va[4*i+3] = t.w;
        float4 u = ((const float4*)gb)[i];
        vb[4*i+0] = u.x; vb[4*i+1] = u.y; vb[4*i+2] = u.z; vb[4*i+3] = u.w;
      }
      U16 ua0, ua1, ub0, ub1;
#pragma unroll
      for (int e = 0; e < 8; ++e) {
        ua0.s[e] = f2bf(va[e]);   ua1.s[e] = f2bf(va[8 + e]);
        ub0.s[e] = f2bf(vb[e]);   ub1.s[e] = f2bf(vb[8 + e]);
      }
      *(uint4*)&sA[srow * 32 + scol + 0] = ua0.v;
      *(uint4*)&sA[srow * 32 + scol + 8] = ua1.v;
      *(uint4*)&sB[srow * 32 + scol + 0] = ub0.v;
      *(uint4*)&sB[srow * 32 + scol + 8] = ub1.v;
    }
    __syncthreads();

    const int lrow = lane & 15;
    const int lk   = (lane >> 4) * 8;
    bf16x8 av[4], bv[4];
#pragma unroll
    for (int i = 0; i < 4; ++i)
      av[i] = *(const bf16x8*)&sA[(wr * 64 + i * 16 + lrow) * 32 + lk];
#pragma unroll
    for (int j = 0; j < 4; ++j)
      bv[j] = *(const bf16x8*)&sB[(wc * 64 + j * 16 + lrow) * 32 + lk];
#pragma unroll
    for (int i = 0; i < 4; ++i)
#pragma unroll
      for (int j = 0; j < 4; ++j)
        acc[i][j] = __builtin_amdgcn_mfma_f32_16x16x32_bf16(av[i], bv[j], acc[i][j], 0, 0, 0);
    __syncthreads();
  }

  const int orow = row0 + wr * 64 + (lane >> 4) * 4;
  const int ocol = col0 + wc * 64 + (lane & 15);
#pragma unroll
  for (int i = 0; i < 4; ++i)
#pragma unroll
    for (int j = 0; j < 4; ++j)
#pragma unroll
      for (int r = 0; r < 4; ++r)
        QKV[(size_t)(orow + i * 16 + r) * NQKV + ocol + j * 16] = f2bf(acc[i][j][r]);
}

// ---------------------------------------------------------------------------
// Chunked causal flash attention (v10): block = 2 waves, 64 q (tile qt),
// chunk c of nc = ceil((qt+1)/8). 2560 near-equal blocks, LDS 32KB.
// ---------------------------------------------------------------------------
__global__ __launch_bounds__(128, 4) void attn_ch(const unsigned short* __restrict__ QKV,
                                                  float* __restrict__ Out,
                                                  unsigned short* __restrict__ Opart,
                                                  float* __restrict__ ML) {
  __shared__ unsigned short sK [2][64 * 64];   // [subtile] 16KB
  __shared__ unsigned short sVt[2][64 * 64];   // 16KB

  const int tid  = threadIdx.x;
  const int lane = tid & 63;
  const int wave = tid >> 6;            // 0..1
  const int l31  = lane & 31;
  const int hi   = lane >> 5;

  const int e  = blockIdx.x;            // 0..79 (round-6 slot mapping)
  int qt, c, nc;
  if (e < 8)       { qt = e;                    c = 0;      nc = 1; }
  else if (e < 24) { int u = e - 8;  qt = 8  + (u >> 1); c = u & 1;  nc = 2; }
  else if (e < 48) { int u = e - 24; qt = 16 + u / 3;    c = u % 3;  nc = 3; }
  else             { int u = e - 48; qt = 24 + (u >> 2); c = u & 3;  nc = 4; }

  const int bh = blockIdx.y;
  const int b = bh >> 4, h = bh & 15;

  const int T0 = 8 * c;
  const int T1 = min(8 * c + 8, qt + 1);
  const int count = T1 - T0;
  const int np  = count >> 1;
  const int odd = count & 1;
  const int nsteps = np + odd;

  const unsigned short* Qbase = QKV + (size_t)(b * TOKENS) * NQKV + h * HDIM;
  const unsigned short* Kbase = Qbase + D_MODEL;
  const unsigned short* Vbase = Kbase + D_MODEL;

  const int qcol = qt * 64 + wave * 32 + l31;

  // ---- Q B-frags (pre-scaled) ----
  bf16x8 qf[4];
  {
    const unsigned short* qrow = Qbase + (size_t)qcol * NQKV + hi * 8;
    union { unsigned short us[8]; bf16x8 v; ushort4 q[2]; } t;
#pragma unroll
    for (int dk = 0; dk < 4; ++dk) {
      t.q[0] = ((const ushort4*)(qrow + dk * 16))[0];
      t.q[1] = ((const ushort4*)(qrow + dk * 16))[1];
#pragma unroll
      for (int ee = 0; ee < 8; ++ee) t.us[ee] = f2bf(bf2f(t.us[ee]) * SCALE);
      qf[dk] = t.v;
    }
  }

  f32x16 o0, o1;
#pragma unroll
  for (int r = 0; r < 16; ++r) { o0[r] = 0.f; o1[r] = 0.f; }
  float m = -1e30f, l = 0.f;

  // ---- staging maps (128 threads) ----
  const int lane16 = lane * 16;
  const int vk0 = (tid & 15) * 4;       // V: 4 keys
  const int vd0 = (tid >> 4) * 8;       // V: 8 dims

  union VU { uint4 v; unsigned short us[8]; };
  VU va0, va1, va2, va3, vb0, vb1, vb2, vb3;

// K: global_load_lds, row-permuted (swapbits23) + (row&7)<<4 pre-swizzled src.
#define KGLOAD1(sb, kt)                                                        \
  {                                                                            \
    _Pragma("unroll")                                                          \
    for (int g = 0; g < 4; ++g) {                                              \
      const int d = g * 2048 + wave * 1024 + lane16;                           \
      const int row = d >> 7;                                                  \
      const int grow = (row & 51) | ((row & 4) << 1) | ((row & 8) >> 1);       \
      const int cb = (d & 127) ^ ((row & 7) << 4);                             \
      GLOAD16(Kbase + (size_t)((kt) * 64 + grow) * NQKV + (cb >> 1),           \
              (char*)&sK[sb][0] + d);                                          \
    }                                                                          \
  }

#define VLOAD1(kt, r0, r1, r2, r3)                                             \
  {                                                                            \
    const unsigned short* vs = Vbase + (size_t)((kt) * 64 + vk0) * NQKV + vd0; \
    r0.v = *(const uint4*)(vs);                                                \
    r1.v = *(const uint4*)(vs + NQKV);                                         \
    r2.v = *(const uint4*)(vs + 2 * NQKV);                                     \
    r3.v = *(const uint4*)(vs + 3 * NQKV);                                     \
  }

#define VWRITE8(sb, r0, r1, r2, r3)                                            \
  {                                                                            \
    char* dV = (char*)&sVt[sb][0];                                             \
    _Pragma("unroll")                                                          \
    for (int ee = 0; ee < 8; ++ee) {                                           \
      const int dim = vd0 + ee;                                                \
      uint2 w;                                                                 \
      w.x = (unsigned)r0.us[ee] | ((unsigned)r1.us[ee] << 16);                 \
      w.y = (unsigned)r2.us[ee] | ((unsigned)r3.us[ee] << 16);                 \
      *(uint2*)(dV + ((dim * 128 + vk0 * 2) ^ ((dim & 7) << 4))) = w;          \
    }                                                                          \
  }

#define QKT(cK, rowbase, st)                                                   \
  {                                                                            \
    _Pragma("unroll")                                                          \
    for (int dk = 0; dk < 4; ++dk) {                                           \
      const int row = (rowbase);                                               \
      bf16x8 kf = *(const bf16x8*)((cK) + ((row * 128 + hi * 16 + dk * 32) ^ ((row & 7) << 4))); \
      st = __builtin_amdgcn_mfma_f32_32x32x16_bf16(kf, qf[dk], st, 0, 0, 0);   \
    }                                                                          \
  }

#define PV4(cV, bpX, bpY, koff)                                                \
  {                                                                            \
    const int r0_ = l31, r1_ = l31 + 32;                                       \
    bf16x8 vf;                                                                 \
    vf = *(const bf16x8*)((cV) + ((r0_ * 128 + hi * 16 + (koff)) ^ ((r0_ & 7) << 4)));      \
    o0 = __builtin_amdgcn_mfma_f32_32x32x16_bf16(vf, bpX, o0, 0, 0, 0);        \
    vf = *(const bf16x8*)((cV) + ((r1_ * 128 + hi * 16 + (koff)) ^ ((r1_ & 7) << 4)));      \
    o1 = __builtin_amdgcn_mfma_f32_32x32x16_bf16(vf, bpX, o1, 0, 0, 0);        \
    vf = *(const bf16x8*)((cV) + ((r0_ * 128 + hi * 16 + (koff) + 32) ^ ((r0_ & 7) << 4))); \
    o0 = __builtin_amdgcn_mfma_f32_32x32x16_bf16(vf, bpY, o0, 0, 0, 0);        \
    vf = *(const bf16x8*)((cV) + ((r1_ * 128 + hi * 16 + (koff) + 32) ^ ((r1_ & 7) << 4))); \
    o1 = __builtin_amdgcn_mfma_f32_32x32x16_bf16(vf, bpY, o1, 0, 0, 0);        \
  }

#define SUBSTEP(cK, cV, tile, diagF)                                           \
  {                                                                            \
    const bool diag  = (diagF);                                                \
    const bool do_hi = !(diag && wave == 0);                                   \
    f32x16 st0, st1;                                                           \
    _Pragma("unroll")                                                          \
    for (int r = 0; r < 16; ++r) { st0[r] = 0.f; st1[r] = 0.f; }               \
    QKT(cK, l31, st0);                                                         \
    if (do_hi) QKT(cK, l31 + 32, st1);                                         \
    if (diag) {                                                                \
      const int kbase = (tile) * 64;                                           \
      _Pragma("unroll")                                                        \
      for (int r = 0; r < 16; ++r) {                                           \
        const int key0 = kbase + (r & 7) + ((r & 8) << 1) + 8 * hi;            \
        if (key0 > qcol) st0[r] = -1e30f;                                      \
        if (do_hi && key0 + 32 > qcol) st1[r] = -1e30f;                        \
      }                                                                        \
    }                                                                          \
    float mx = do_hi ? max32t(st0, st1) : max32t(st0, st0);                    \
    mx = fmaxf(mx, xchg32(mx));                                                \
    if (!__all(mx - m <= 8.f)) {                                               \
      const float mnew = fmaxf(m, mx);                                         \
      const float corr = exp2f(m - mnew);                                      \
      m = mnew;                                                                \
      l *= corr;                                                               \
      _Pragma("unroll")                                                        \
      for (int r = 0; r < 16; ++r) { o0[r] *= corr; o1[r] *= corr; }           \
    }                                                                          \
    float p0[16], p1[16];                                                      \
    _Pragma("unroll")                                                          \
    for (int r = 0; r < 16; ++r) p0[r] = exp2f(st0[r] - m);                    \
    float ps;                                                                  \
    if (do_hi) {                                                               \
      _Pragma("unroll")                                                        \
      for (int r = 0; r < 16; ++r) p1[r] = exp2f(st1[r] - m);                  \
      ps = sum32t(p0, p1);                                                     \
    } else {                                                                   \
      float z[16];                                                             \
      _Pragma("unroll")                                                        \
      for (int r = 0; r < 16; ++r) z[r] = 0.f;                                 \
      ps = sum32t(p0, z);                                                      \
    }                                                                          \
    ps += xchg32(ps);                                                          \
    l += ps;                                                                   \
    bf16x8 f0 = pfrag8(&p0[0]), f1 = pfrag8(&p0[8]);                           \
    PV4(cV, f0, f1, 0);                                                        \
    if (do_hi) {                                                               \
      bf16x8 f2 = pfrag8(&p1[0]), f3 = pfrag8(&p1[8]);                         \
      PV4(cV, f2, f3, 64);                                                     \
    }                                                                          \
  }

  // ---- prologue V load for step 0 ----
  {
    const int ta = T0;
    const int tb = min(T0 + 1, T1 - 1);
    VLOAD1(ta, va0, va1, va2, va3);
    VLOAD1(tb, vb0, vb1, vb2, vb3);
  }

#pragma unroll 1
  for (int i = 0; i < nsteps; ++i) {
    const int ta = T0 + 2 * i;
    const int tb = min(ta + 1, T1 - 1);
    const bool is_pair = (i < np);

    __syncthreads();                     // prior compute done reading buf
    KGLOAD1(0, ta);
    KGLOAD1(1, tb);
    VWRITE8(0, va0, va1, va2, va3);
    VWRITE8(1, vb0, vb1, vb2, vb3);
    const bool more = (i + 1 < nsteps);
    if (more) {
      const int na = T0 + 2 * (i + 1);
      const int nb = min(na + 1, T1 - 1);
      VLOAD1(na, va0, va1, va2, va3);
      VLOAD1(nb, vb0, vb1, vb2, vb3);
    }
    if (more) asm volatile("s_waitcnt vmcnt(8)" ::: "memory");
    else      asm volatile("s_waitcnt vmcnt(0)" ::: "memory");
    asm volatile("s_waitcnt lgkmcnt(0)" ::: "memory");
    __builtin_amdgcn_s_barrier();

    SUBSTEP((const char*)&sK[0][0], (const char*)&sVt[0][0], ta, ta == qt);
    if (is_pair)
      SUBSTEP((const char*)&sK[1][0], (const char*)&sVt[1][0], tb, tb == qt);
  }

  // ---- output ----
  if (nc == 1) {
    const float inv = 1.f / l;
    float* orow = Out + (size_t)(b * TOKENS + qcol) * D_MODEL + h * HDIM;
#pragma unroll
    for (int g = 0; g < 4; ++g) {
      float4 w0, w1;
      w0.x = o0[4*g+0] * inv; w0.y = o0[4*g+1] * inv;
      w0.z = o0[4*g+2] * inv; w0.w = o0[4*g+3] * inv;
      w1.x = o1[4*g+0] * inv; w1.y = o1[4*g+1] * inv;
      w1.z = o1[4*g+2] * inv; w1.w = o1[4*g+3] * inv;
      *(float4*)(orow + 8 * g + 4 * hi)      = w0;
      *(float4*)(orow + 8 * g + 4 * hi + 32) = w1;
    }
  } else {
    const int qloc = wave * 32 + l31;
    unsigned short* ob = Opart + ((size_t)(bh * 80 + e)) * 4096 + qloc * 64;
#pragma unroll
    for (int g = 0; g < 4; ++g) {
      uint2 w0, w1;
      w0.x = cvt_pk_bf16(o0[4*g+0], o0[4*g+1]);
      w0.y = cvt_pk_bf16(o0[4*g+2], o0[4*g+3]);
      w1.x = cvt_pk_bf16(o1[4*g+0], o1[4*g+1]);
      w1.y = cvt_pk_bf16(o1[4*g+2], o1[4*g+3]);
      *(uint2*)(ob + 8 * g + 4 * hi)      = w0;
      *(uint2*)(ob + 8 * g + 4 * hi + 32) = w1;
    }
    if (hi == 0) {
      float2 t2; t2.x = m; t2.y = l;
      ((float2*)ML)[((size_t)(bh * 80 + e)) * 64 + qloc] = t2;
    }
  }
#undef KGLOAD1
#undef VLOAD1
#undef VWRITE8
#undef QKT
#undef PV4
#undef SUBSTEP
}

// ---------------------------------------------------------------------------
// Merge (round-6 verified verbatim): combine nc partials per (bh, qt>=8, q).
// ---------------------------------------------------------------------------
__global__ __launch_bounds__(256) void merge_split(const unsigned short* __restrict__ Opart,
                                                   const float* __restrict__ ML,
                                                   float* __restrict__ Out) {
  const int qt = 8 + blockIdx.x;        // 8..31
  const int bh = blockIdx.y;
  const int b = bh >> 4, h = bh & 15;
  int nc, slot0;
  if (qt < 16)      { nc = 2; slot0 = 8  + (qt - 8)  * 2; }
  else if (qt < 24) { nc = 3; slot0 = 24 + (qt - 16) * 3; }
  else              { nc = 4; slot0 = 48 + (qt - 24) * 4; }

  const int q  = threadIdx.x >> 2;
  const int d0 = (threadIdx.x & 3) * 16;

  float m[4], l[4];
  float M = -1e30f;
#pragma unroll 1
  for (int si = 0; si < nc; ++si) {
    float2 t = ((const float2*)ML)[((size_t)(bh * 80 + slot0 + si)) * 64 + q];
    m[si] = t.x; l[si] = t.y;
    M = fmaxf(M, t.x);
  }
  float L = 0.f, w[4];
#pragma unroll 1
  for (int si = 0; si < nc; ++si) { w[si] = exp2f(m[si] - M); L += l[si] * w[si]; }
  const float invL = 1.f / L;

  float acc[16];
#pragma unroll
  for (int i = 0; i < 16; ++i) acc[i] = 0.f;
#pragma unroll 1
  for (int si = 0; si < nc; ++si) {
    const unsigned short* ob = Opart + ((size_t)(bh * 80 + slot0 + si)) * 4096 + q * 64 + d0;
    ushort4 u0 = ((const ushort4*)ob)[0];
    ushort4 u1 = ((const ushort4*)ob)[1];
    ushort4 u2 = ((const ushort4*)ob)[2];
    ushort4 u3 = ((const ushort4*)ob)[3];
    const float ws = w[si];
    acc[0]  += bf2f(u0.x) * ws; acc[1]  += bf2f(u0.y) * ws;
    acc[2]  += bf2f(u0.z) * ws; acc[3]  += bf2f(u0.w) * ws;
    acc[4]  += bf2f(u1.x) * ws; acc[5]  += bf2f(u1.y) * ws;
    acc[6]  += bf2f(u1.z) * ws; acc[7]  += bf2f(u1.w) * ws;
    acc[8]  += bf2f(u2.x) * ws; acc[9]  += bf2f(u2.y) * ws;
    acc[10] += bf2f(u2.z) * ws; acc[11] += bf2f(u2.w) * ws;
    acc[12] += bf2f(u3.x) * ws; acc[13] += bf2f(u3.y) * ws;
    acc[14] += bf2f(u3.z) * ws; acc[15] += bf2f(u3.w) * ws;
  }
  float* orow = Out + (size_t)(b * TOKENS + qt * 64 + q) * D_MODEL + h * HDIM + d0;
#pragma unroll
  for (int i = 0; i < 4; ++i) {
    float4 o;
    o.x = acc[4*i+0] * invL; o.y = acc[4*i+1] * invL;
    o.z = acc[4*i+2] * invL; o.w = acc[4*i+3] * invL;
    ((float4*)orow)[i] = o;
  }
}

// ---------------------------------------------------------------------------
// Fallback attention (round-12 verified attn9) for mid-size ws.
// ---------------------------------------------------------------------------
__global__ __launch_bounds__(256, 2) void attn9(const unsigned short* __restrict__ QKV,
                                                float* __restrict__ Out) {
  __shared__ unsigned short sK [2][2][64 * 64];
  __shared__ unsigned short sVt[2][2][64 * 64];

  const int tid  = threadIdx.x;
  const int lane = tid & 63;
  const int wave = tid >> 6;
  const int l31  = lane & 31;
  const int hi   = lane >> 5;

  const int x = blockIdx.x;
  int bh, u;
  if (x < 256) { bh = x & 31; u = x >> 5; }
  else         { const int x2 = x - 256; bh = x2 & 31; u = 15 - (x2 >> 5); }

  const int b = bh >> 4, h = bh & 15;
  const int q0w  = u * 128 + wave * 32;
  const int qcol = q0w + l31;

  const unsigned short* Qbase = QKV + (size_t)(b * TOKENS) * NQKV + h * HDIM;
  const unsigned short* Kbase = Qbase + D_MODEL;
  const unsigned short* Vbase = Kbase + D_MODEL;

  bf16x8 qf[4];
  {
    const unsigned short* qrow = Qbase + (size_t)qcol * NQKV + hi * 8;
    union { unsigned short us[8]; bf16x8 v; ushort4 q[2]; } t;
#pragma unroll
    for (int dk = 0; dk < 4; ++dk) {
      t.q[0] = ((const ushort4*)(qrow + dk * 16))[0];
      t.q[1] = ((const ushort4*)(qrow + dk * 16))[1];
#pragma unroll
      for (int e = 0; e < 8; ++e) t.us[e] = f2bf(bf2f(t.us[e]) * SCALE);
      qf[dk] = t.v;
    }
  }

  f32x16 o0, o1;
#pragma unroll
  for (int r = 0; r < 16; ++r) { o0[r] = 0.f; o1[r] = 0.f; }
  float m = -1e30f, l = 0.f;

  const int vk0 = (tid & 15) * 4;
  const int vd0 = (tid >> 4) * 4;
  ushort4 va0, va1, va2, va3, vb0, vb1, vb2, vb3;

  const int lane16 = lane * 16;

#define KGLOAD(kt, buf, s)                                                     \
  {                                                                            \
    _Pragma("unroll")                                                          \
    for (int g = 0; g < 2; ++g) {                                              \
      const int base = g * 4096 + wave * 1024;                                 \
      const int d = base + lane16;                                             \
      const int row = d >> 7;                                                  \
      const int grow = (row & 51) | ((row & 4) << 1) | ((row & 8) >> 1);       \
      const int cb = (d & 127) ^ ((row & 7) << 4);                             \
      GLOAD16(Kbase + (size_t)((kt) * 64 + grow) * NQKV + (cb >> 1),           \
              (char*)&sK[buf][s][0] + base + lane16);                          \
    }                                                                          \
  }

#define VLOAD2(pp)                                                             \
  {                                                                            \
    const unsigned short* vsA = Vbase + (size_t)((2*(pp)) * 64 + vk0) * NQKV + vd0;   \
    va0 = *(const ushort4*)(vsA);                                              \
    va1 = *(const ushort4*)(vsA + NQKV);                                       \
    va2 = *(const ushort4*)(vsA + 2 * NQKV);                                   \
    va3 = *(const ushort4*)(vsA + 3 * NQKV);                                   \
    const unsigned short* vsB = Vbase + (size_t)((2*(pp)+1) * 64 + vk0) * NQKV + vd0; \
    vb0 = *(const ushort4*)(vsB);                                              \
    vb1 = *(const ushort4*)(vsB + NQKV);                                       \
    vb2 = *(const ushort4*)(vsB + 2 * NQKV);                                   \
    vb3 = *(const ushort4*)(vsB + 3 * NQKV);                                   \
  }

#define VWRITE1(buf, s, t0, t1, t2, t3)                                        \
  {                                                                            \
    ushort4 c0, c1, c2, c3;                                                    \
    c0.x = t0.x; c0.y = t1.x; c0.z = t2.x; c0.w = t3.x;                        \
    c1.x = t0.y; c1.y = t1.y; c1.z = t2.y; c1.w = t3.y;                        \
    c2.x = t0.z; c2.y = t1.z; c2.z = t2.z; c2.w = t3.z;                        \
    c3.x = t0.w; c3.y = t1.w; c3.z = t2.w; c3.w = t3.w;                        \
    char* dV = (char*)&sVt[buf][s][0];                                         \
    _Pragma("unroll")                                                          \
    for (int e = 0; e < 4; ++e) {                                              \
      const int dim = vd0 + e;                                                 \
      const int o2 = (dim * 128 + vk0 * 2) ^ ((dim & 7) << 4);                 \
      ushort4 cc = (e == 0) ? c0 : (e == 1) ? c1 : (e == 2) ? c2 : c3;         \
      *(ushort4*)(dV + o2) = cc;                                               \
    }                                                                          \
  }

#define QKT(cK, rowbase, st)                                                   \
  {                                                                            \
    _Pragma("unroll")                                                          \
    for (int dk = 0; dk < 4; ++dk) {                                           \
      const int row = (rowbase);                                               \
      bf16x8 kf = *(const bf16x8*)((cK) + ((row * 128 + hi * 16 + dk * 32) ^ ((row & 7) << 4))); \
      st = __builtin_amdgcn_mfma_f32_32x32x16_bf16(kf, qf[dk], st, 0, 0, 0);   \
    }                                                                          \
  }

#define PV4(cV, bpX, bpY, koff)                                                \
  {                                                                            \
    const int r0 = l31, r1 = l31 + 32;                                         \
    bf16x8 vf;                                                                 \
    vf = *(const bf16x8*)((cV) + ((r0 * 128 + hi * 16 + (koff)) ^ ((r0 & 7) << 4)));      \
    o0 = __builtin_amdgcn_mfma_f32_32x32x16_bf16(vf, bpX, o0, 0, 0, 0);        \
    vf = *(const bf16x8*)((cV) + ((r1 * 128 + hi * 16 + (koff)) ^ ((r1 & 7) << 4)));      \
    o1 = __builtin_amdgcn_mfma_f32_32x32x16_bf16(vf, bpX, o1, 0, 0, 0);        \
    vf = *(const bf16x8*)((cV) + ((r0 * 128 + hi * 16 + (koff) + 32) ^ ((r0 & 7) << 4))); \
    o0 = __builtin_amdgcn_mfma_f32_32x32x16_bf16(vf, bpY, o0, 0, 0, 0);        \
    vf = *(const bf16x8*)((cV) + ((r1 * 128 + hi * 16 + (koff) + 32) ^ ((r1 & 7) << 4))); \
    o1 = __builtin_amdgcn_mfma_f32_32x32x16_bf16(vf, bpY, o1, 0, 0, 0);        \
  }

  KGLOAD(0, 0, 0);
  KGLOAD(1, 0, 1);
  VLOAD2(0);
  VWRITE1(0, 0, va0, va1, va2, va3);
  VWRITE1(0, 1, vb0, vb1, vb2, vb3);
  __syncthreads();

#pragma unroll 1
  for (int p = 0; p < u; ++p) {
    const int cur = p & 1;
    KGLOAD(2 * (p + 1),     cur ^ 1, 0);
    KGLOAD(2 * (p + 1) + 1, cur ^ 1, 1);
    VLOAD2(p + 1);

    const char* cKA = (const char*)&sK[cur][0][0];
    const char* cKB = (const char*)&sK[cur][1][0];
    const char* cVA = (const char*)&sVt[cur][0][0];
    const char* cVB = (const char*)&sVt[cur][1][0];

    f32x16 sA0, sA1, sB0, sB1;
#pragma unroll
    for (int r = 0; r < 16; ++r) { sA0[r] = 0.f; sA1[r] = 0.f; sB0[r] = 0.f; sB1[r] = 0.f; }

    QKT(cKA, l31,      sA0);
    QKT(cKA, l31 + 32, sA1);
    QKT(cKB, l31,      sB0);
    QKT(cKB, l31 + 32, sB1);

    {
      float mx = max32t(sA0, sA1);
      mx = fmaxf(mx, xchg32(mx));
      if (!__all(mx - m <= 8.f)) {
        const float mnew = fmaxf(m, mx);
        const float corr = exp2f(m - mnew);
        m = mnew;
        l *= corr;
#pragma unroll
        for (int r = 0; r < 16; ++r) { o0[r] *= corr; o1[r] *= corr; }
      }
      float pA0[16], pA1[16];
#pragma unroll
      for (int r = 0; r < 16; ++r) { pA0[r] = exp2f(sA0[r] - m); pA1[r] = exp2f(sA1[r] - m); }
      float ps = sum32t(pA0, pA1);
      ps += xchg32(ps);
      l += ps;
      bf16x8 a0 = pfrag8(&pA0[0]), a1 = pfrag8(&pA0[8]);
      bf16x8 a2 = pfrag8(&pA1[0]), a3 = pfrag8(&pA1[8]);
      PV4(cVA, a0, a1, 0);
      PV4(cVA, a2, a3, 64);
    }

    {
      float mx = max32t(sB0, sB1);
      mx = fmaxf(mx, xchg32(mx));
      if (!__all(mx - m <= 8.f)) {
        const float mnew = fmaxf(m, mx);
        const float corr = exp2f(m - mnew);
        m = mnew;
        l *= corr;
#pragma unroll
        for (int r = 0; r < 16; ++r) { o0[r] *= corr; o1[r] *= corr; }
      }
      float pB0[16], pB1[16];
#pragma unroll
      for (int r = 0; r < 16; ++r) { pB0[r] = exp2f(sB0[r] - m); pB1[r] = exp2f(sB1[r] - m); }
      float ps = sum32t(pB0, pB1);
      ps += xchg32(ps);
      l += ps;
      bf16x8 b0 = pfrag8(&pB0[0]), b1 = pfrag8(&pB0[8]);
      bf16x8 b2 = pfrag8(&pB1[0]), b3 = pfrag8(&pB1[8]);
      PV4(cVB, b0, b1, 0);
      PV4(cVB, b2, b3, 64);
    }

    VWRITE1(cur ^ 1, 0, va0, va1, va2, va3);
    VWRITE1(cur ^ 1, 1, vb0, vb1, vb2, vb3);
    __syncthreads();
  }

  {
    const int cur = u & 1;
    const char* cK[2] = { (const char*)&sK[cur][0][0], (const char*)&sK[cur][1][0] };
    const char* cV[2] = { (const char*)&sVt[cur][0][0], (const char*)&sVt[cur][1][0] };
    const int nsub = (wave >= 2) ? 2 : 1;
#pragma unroll 1
    for (int s = 0; s < nsub; ++s) {
      const int kbase = u * 128 + s * 64;
      const bool diag  = (wave >= 2) ? (s == 1) : true;
      const bool do_hi = diag ? ((wave & 1) == 1) : true;

      f32x16 st0, st1;
#pragma unroll
      for (int r = 0; r < 16; ++r) { st0[r] = 0.f; st1[r] = 0.f; }

      QKT(cK[s], l31, st0);
      if (do_hi) QKT(cK[s], l31 + 32, st1);

      if (diag) {
#pragma unroll
        for (int r = 0; r < 16; ++r) {
          const int key0 = kbase + (r & 7) + ((r & 8) << 1) + 8 * hi;
          if (key0 > qcol) st0[r] = -1e30f;
          if (do_hi && key0 + 32 > qcol) st1[r] = -1e30f;
        }
      }

      float mx = do_hi ? max32t(st0, st1) : max32t(st0, st0);
      mx = fmaxf(mx, xchg32(mx));

      if (!__all(mx - m <= 8.f)) {
        const float mnew = fmaxf(m, mx);
        const float corr = exp2f(m - mnew);
        m = mnew;
        l *= corr;
#pragma unroll
        for (int r = 0; r < 16; ++r) { o0[r] *= corr; o1[r] *= corr; }
      }

      float p0[16], p1[16];
#pragma unroll
      for (int r = 0; r < 16; ++r) p0[r] = exp2f(st0[r] - m);
      float ps;
      if (do_hi) {
#pragma unroll
        for (int r = 0; r < 16; ++r) p1[r] = exp2f(st1[r] - m);
        ps = sum32t(p0, p1);
      } else {
        float z[16];
#pragma unroll
        for (int r = 0; r < 16; ++r) z[r] = 0.f;
        ps = sum32t(p0, z);
      }
      ps += xchg32(ps);
      l += ps;

      bf16x8 c0 = pfrag8(&p0[0]), c1 = pfrag8(&p0[8]);
      PV4(cV[s], c0, c1, 0);
      if (do_hi) {
        bf16x8 c2 = pfrag8(&p1[0]), c3 = pfrag8(&p1[8]);
        PV4(cV[s], c2, c3, 64);
      }
    }
  }

  {
    const float inv = 1.f / l;
    float* orow = Out + (size_t)(b * TOKENS + qcol) * D_MODEL + h * HDIM;
#pragma unroll
    for (int g = 0; g < 4; ++g) {
      float4 w0, w1;
      w0.x = o0[4*g+0] * inv; w0.y = o0[4*g+1] * inv;
      w0.z = o0[4*g+2] * inv; w0.w = o0[4*g+3] * inv;
      w1.x = o1[4*g+0] * inv; w1.y = o1[4*g+1] * inv;
      w1.z = o1[4*g+2] * inv; w1.w = o1[4*g+3] * inv;
      *(float4*)(orow + 8 * g + 4 * hi)      = w0;
      *(float4*)(orow + 8 * g + 4 * hi + 32) = w1;
    }
  }
}

extern "C" void kernel_launch(void* const* d_in, const int* in_sizes, int n_in,
                              void* d_out, int out_size, void* d_ws, size_t ws_size,
                              hipStream_t stream) {
  const float* X = (const float*)d_in[0];
  const float* W = (const float*)d_in[1];
  float* Out = (float*)d_out;
  unsigned short* QKV = (unsigned short*)d_ws;

  const size_t QKV_E   = (size_t)MROWS * NQKV;
  const size_t XB_E    = (size_t)MROWS * D_MODEL;
  const size_t WB_E    = (size_t)NQKV * D_MODEL;
  const size_t OPART_E = (size_t)32 * 80 * 4096;
  const size_t ML_B    = (size_t)32 * 80 * 64 * 2 * sizeof(float);

  const size_t need_bf16  = (QKV_E + XB_E + WB_E) * 2;
  const size_t need_split = need_bf16 + OPART_E * 2 + ML_B;

  if (ws_size >= need_bf16) {
    unsigned short* Xb = QKV + QKV_E;
    unsigned short* Wb = Xb + XB_E;
    cvt_bf16<<<(XB_E + WB_E) / (256 * 8), 256, 0, stream>>>(X, W, Xb, Wb);
    gemm8<<<dim3(MROWS / 256, NQKV / 256), 512, 0, stream>>>(Xb, Wb, QKV);
  } else {
    qkv_gemm<<<dim3(MROWS / 128, NQKV / 128), 256, 0, stream>>>(X, W, QKV);
  }

  if (ws_size >= need_split) {
    unsigned short* Opart = QKV + QKV_E + XB_E + WB_E;
    float* ML = (float*)(Opart + OPART_E);
    attn_ch<<<dim3(80, 2 * HEADS), 128, 0, stream>>>(QKV, Out, Opart, ML);
    merge_split<<<dim3(24, 2 * HEADS), 256, 0, stream>>>(Opart, ML, Out);
  } else {
    attn9<<<512, 256, 0, stream>>>(QKV, Out);
  }
}

// Round 16
// 101.770 us; speedup vs baseline: 1.4824x; 1.4824x over previous
//
#include <hip/hip_runtime.h>
#include <hip/hip_bf16.h>
#include <stdint.h>

#define D_MODEL 1024
#define TOKENS  2048
#define HEADS   16
#define HDIM    64
#define NQKV    3072      // 3*D_MODEL
#define MROWS   4096      // BATCH*TOKENS
#define SCALE   0.18033688011112042f   // 0.125 * log2(e)

typedef __attribute__((ext_vector_type(4)))  float f32x4;
typedef __attribute__((ext_vector_type(16))) float f32x16;
typedef __attribute__((ext_vector_type(8)))  short bf16x8;

__device__ __forceinline__ unsigned short f2bf(float f) {
  union { float f; unsigned u; } v; v.f = f;
  unsigned u = v.u + 0x7FFFu + ((v.u >> 16) & 1u);   // RNE
  return (unsigned short)(u >> 16);
}
__device__ __forceinline__ float bf2f(unsigned short b) {
  union { unsigned u; float f; } v; v.u = ((unsigned)b) << 16;
  return v.f;
}
__device__ __forceinline__ unsigned cvt_pk_bf16(float lo, float hi) {
  unsigned r;
  asm("v_cvt_pk_bf16_f32 %0, %1, %2" : "=v"(r) : "v"(lo), "v"(hi));
  return r;
}
__device__ __forceinline__ float xchg32(float v) {
  return __shfl_xor(v, 32);
}
__device__ __forceinline__ bf16x8 pfrag8(const float* g) {
  union { uint4 u; bf16x8 v; } r;
  r.u.x = cvt_pk_bf16(g[0], g[1]);
  r.u.y = cvt_pk_bf16(g[2], g[3]);
  r.u.z = cvt_pk_bf16(g[4], g[5]);
  r.u.w = cvt_pk_bf16(g[6], g[7]);
  return r.v;
}
__device__ __forceinline__ float max32t(const f32x16& a, const f32x16& b) {
  float t[16];
#pragma unroll
  for (int r = 0; r < 16; ++r) t[r] = fmaxf(a[r], b[r]);
#pragma unroll
  for (int s = 8; s > 0; s >>= 1)
#pragma unroll
    for (int r = 0; r < s; ++r) t[r] = fmaxf(t[r], t[r + s]);
  return t[0];
}
__device__ __forceinline__ float sum32t(const float* a, const float* b) {
  float t[16];
#pragma unroll
  for (int r = 0; r < 16; ++r) t[r] = a[r] + b[r];
#pragma unroll
  for (int s = 8; s > 0; s >>= 1)
#pragma unroll
    for (int r = 0; r < s; ++r) t[r] = t[r] + t[r + s];
  return t[0];
}

#define GLOAD16(g, l)                                                          \
  __builtin_amdgcn_global_load_lds(                                            \
      (const __attribute__((address_space(1))) unsigned int*)(g),              \
      (__attribute__((address_space(3))) unsigned int*)(l), 16, 0, 0)

// ---------------------------------------------------------------------------
// fp32 -> bf16 convert pass (X then W, contiguous).
// ---------------------------------------------------------------------------
__global__ __launch_bounds__(256) void cvt_bf16(const float* __restrict__ X,
                                                const float* __restrict__ W,
                                                unsigned short* __restrict__ Xb,
                                                unsigned short* __restrict__ Wb) {
  const size_t NX = (size_t)MROWS * D_MODEL;
  size_t i = ((size_t)blockIdx.x * 256 + threadIdx.x) * 8;
  const float* src; unsigned short* dst; size_t off;
  if (i < NX) { src = X; dst = Xb; off = i; }
  else        { src = W; dst = Wb; off = i - NX; }
  float4 a = ((const float4*)(src + off))[0];
  float4 b = ((const float4*)(src + off))[1];
  union { unsigned short s[8]; uint4 v; } u;
  u.s[0] = f2bf(a.x); u.s[1] = f2bf(a.y); u.s[2] = f2bf(a.z); u.s[3] = f2bf(a.w);
  u.s[4] = f2bf(b.x); u.s[5] = f2bf(b.y); u.s[6] = f2bf(b.z); u.s[7] = f2bf(b.w);
  *(uint4*)(dst + off) = u.v;
}

// ---------------------------------------------------------------------------
// 8-phase 256x256 GEMM with full (row&7)<<4 XOR swizzle (round-15 verified).
// ---------------------------------------------------------------------------
__global__ __launch_bounds__(512, 1) void gemm8(const unsigned short* __restrict__ A,
                                                const unsigned short* __restrict__ B,
                                                unsigned short* __restrict__ C) {
  __shared__ unsigned short sA[2][2][128][64];
  __shared__ unsigned short sB[2][2][128][64];

  const int tid  = threadIdx.x;
  const int lane = tid & 63;
  const int wave = tid >> 6;
  const int wr   = wave >> 2;
  const int wc   = wave & 3;
  const int l15  = lane & 15;
  const int lg   = lane >> 4;

  const int bm = blockIdx.x;
  const int bn = blockIdx.y;

  f32x4 acc[8][4];
#pragma unroll
  for (int i = 0; i < 8; ++i)
#pragma unroll
    for (int j = 0; j < 4; ++j)
#pragma unroll
      for (int r = 0; r < 4; ++r) acc[i][j][r] = 0.f;

  const int srow = tid >> 3;
  const int scb  = (tid & 7) * 16;
  const int ssce = (scb ^ ((srow & 7) << 4)) >> 1;

  const unsigned short* Ag = A + (size_t)(bm * 256) * D_MODEL;
  const unsigned short* Bg = B + (size_t)(bn * 256) * D_MODEL;

#define STG_A(buf, hf, t)                                                      \
  { GLOAD16(Ag + (size_t)((hf) * 128 + srow) * D_MODEL + (t) * 64 + ssce,      \
            (char*)&sA[buf][hf][0][0] + srow * 128 + scb);                     \
    GLOAD16(Ag + (size_t)((hf) * 128 + 64 + srow) * D_MODEL + (t) * 64 + ssce, \
            (char*)&sA[buf][hf][0][0] + 8192 + srow * 128 + scb); }
#define STG_B(buf, hf, t)                                                      \
  { GLOAD16(Bg + (size_t)((hf) * 128 + srow) * D_MODEL + (t) * 64 + ssce,      \
            (char*)&sB[buf][hf][0][0] + srow * 128 + scb);                     \
    GLOAD16(Bg + (size_t)((hf) * 128 + 64 + srow) * D_MODEL + (t) * 64 + ssce, \
            (char*)&sB[buf][hf][0][0] + 8192 + srow * 128 + scb); }

  const char* aBse[2] = { (const char*)&sA[0][wr][0][0], (const char*)&sA[1][wr][0][0] };
  const char* bBse[2] = { (const char*)&sB[0][wc >> 1][0][0], (const char*)&sB[1][wc >> 1][0][0] };
  const int swzl = (l15 & 7) << 4;
  const int cbs0 = (lg * 16) ^ swzl;
  const int cbs1 = (64 + lg * 16) ^ swzl;
  const int arow = l15 * 128;
  const int brow = ((wc & 1) * 64 + l15) * 128;

#define DO_PHASE(qm, qn, buf, STAGE_STMT, DO_VM)                               \
  {                                                                            \
    bf16x8 a_[4][2], b_[2][2];                                                 \
    _Pragma("unroll")                                                          \
    for (int i = 0; i < 4; ++i) {                                              \
      a_[i][0] = *(const bf16x8*)(aBse[buf] + ((qm)*4 + i) * 2048 + arow + cbs0); \
      a_[i][1] = *(const bf16x8*)(aBse[buf] + ((qm)*4 + i) * 2048 + arow + cbs1); \
    }                                                                          \
    _Pragma("unroll")                                                          \
    for (int n = 0; n < 2; ++n) {                                              \
      b_[n][0] = *(const bf16x8*)(bBse[buf] + ((qn)*2 + n) * 2048 + brow + cbs0); \
      b_[n][1] = *(const bf16x8*)(bBse[buf] + ((qn)*2 + n) * 2048 + brow + cbs1); \
    }                                                                          \
    STAGE_STMT;                                                                \
    if (DO_VM) asm volatile("s_waitcnt vmcnt(2)" ::: "memory");                \
    __builtin_amdgcn_s_barrier();                                              \
    asm volatile("s_waitcnt lgkmcnt(0)" ::: "memory");                         \
    __builtin_amdgcn_sched_barrier(0);                                         \
    __builtin_amdgcn_s_setprio(1);                                             \
    _Pragma("unroll")                                                          \
    for (int ks = 0; ks < 2; ++ks)                                             \
      _Pragma("unroll")                                                        \
      for (int i = 0; i < 4; ++i)                                              \
        _Pragma("unroll")                                                      \
        for (int n = 0; n < 2; ++n)                                            \
          acc[(qm)*4 + i][(qn)*2 + n] = __builtin_amdgcn_mfma_f32_16x16x32_bf16( \
              a_[i][ks], b_[n][ks], acc[(qm)*4 + i][(qn)*2 + n], 0, 0, 0);     \
    __builtin_amdgcn_s_setprio(0);                                             \
    __builtin_amdgcn_s_barrier();                                              \
  }

  STG_A(0, 0, 0);
  STG_B(0, 0, 0);
  STG_A(0, 1, 0);
  STG_B(0, 1, 0);
  STG_B(1, 0, 1);
  asm volatile("s_waitcnt vmcnt(2)" ::: "memory");
  __builtin_amdgcn_s_barrier();

#pragma unroll 1
  for (int j = 0; j < 8; ++j) {
    const int t1 = 2 * j + 1;
    const int t2 = 2 * j + 2;
    const int t3 = 2 * j + 3;
    DO_PHASE(0, 0, 0, { STG_A(1, 0, t1); }, 0);
    DO_PHASE(1, 0, 0, { STG_A(1, 1, t1); }, 0);
    DO_PHASE(0, 1, 0, { STG_B(1, 1, t1); }, 0);
    DO_PHASE(1, 1, 0, { if (t2 < 16) STG_B(0, 0, t2); }, 1);
    DO_PHASE(0, 0, 1, { if (t2 < 16) STG_A(0, 0, t2); }, 0);
    DO_PHASE(1, 0, 1, { if (t2 < 16) STG_A(0, 1, t2); }, 0);
    DO_PHASE(0, 1, 1, { if (t2 < 16) STG_B(0, 1, t2); }, 0);
    DO_PHASE(1, 1, 1, { if (t3 < 16) STG_B(1, 0, t3); }, 1);
  }

  const int orow0 = bm * 256 + wr * 128 + lg * 4;
  const int ocol0 = bn * 256 + wc * 64 + l15;
#pragma unroll
  for (int mi = 0; mi < 8; ++mi)
#pragma unroll
    for (int ni = 0; ni < 4; ++ni)
#pragma unroll
      for (int r = 0; r < 4; ++r)
        C[(size_t)(orow0 + mi * 16 + r) * NQKV + ocol0 + ni * 16] = f2bf(acc[mi][ni][r]);
#undef STG_A
#undef STG_B
#undef DO_PHASE
}

// ---------------------------------------------------------------------------
// Fallback fp32-input GEMM for small ws (round-1 verified).
// ---------------------------------------------------------------------------
__global__ __launch_bounds__(256) void qkv_gemm(const float* __restrict__ X,
                                                const float* __restrict__ W,
                                                unsigned short* __restrict__ QKV) {
  __shared__ unsigned short sA[128 * 32];
  __shared__ unsigned short sB[128 * 32];
  const int tid  = threadIdx.x;
  const int lane = tid & 63;
  const int wave = tid >> 6;
  const int wr = wave >> 1, wc = wave & 1;
  const int row0 = blockIdx.x * 128;
  const int col0 = blockIdx.y * 128;

  f32x4 acc[4][4];
#pragma unroll
  for (int i = 0; i < 4; ++i)
#pragma unroll
    for (int j = 0; j < 4; ++j)
#pragma unroll
      for (int r = 0; r < 4; ++r) acc[i][j][r] = 0.f;

  const int srow = tid >> 1;
  const int scol = (tid & 1) * 16;
  union U16 { unsigned short s[8]; uint4 v; };

#pragma unroll 1
  for (int k0 = 0; k0 < D_MODEL; k0 += 32) {
    {
      const float* ga = X + (size_t)(row0 + srow) * D_MODEL + k0 + scol;
      const float* gb = W + (size_t)(col0 + srow) * D_MODEL + k0 + scol;
      float va[16], vb[16];
#pragma unroll
      for (int i = 0; i < 4; ++i) {
        float4 t = ((const float4*)ga)[i];
        va[4*i+0] = t.x; va[4*i+1] = t.y; va[4*i+2] = t.z; va[4*i+3] = t.w;
        float4 u = ((const float4*)gb)[i];
        vb[4*i+0] = u.x; vb[4*i+1] = u.y; vb[4*i+2] = u.z; vb[4*i+3] = u.w;
      }
      U16 ua0, ua1, ub0, ub1;
#pragma unroll
      for (int e = 0; e < 8; ++e) {
        ua0.s[e] = f2bf(va[e]);   ua1.s[e] = f2bf(va[8 + e]);
        ub0.s[e] = f2bf(vb[e]);   ub1.s[e] = f2bf(vb[8 + e]);
      }
      *(uint4*)&sA[srow * 32 + scol + 0] = ua0.v;
      *(uint4*)&sA[srow * 32 + scol + 8] = ua1.v;
      *(uint4*)&sB[srow * 32 + scol + 0] = ub0.v;
      *(uint4*)&sB[srow * 32 + scol + 8] = ub1.v;
    }
    __syncthreads();

    const int lrow = lane & 15;
    const int lk   = (lane >> 4) * 8;
    bf16x8 av[4], bv[4];
#pragma unroll
    for (int i = 0; i < 4; ++i)
      av[i] = *(const bf16x8*)&sA[(wr * 64 + i * 16 + lrow) * 32 + lk];
#pragma unroll
    for (int j = 0; j < 4; ++j)
      bv[j] = *(const bf16x8*)&sB[(wc * 64 + j * 16 + lrow) * 32 + lk];
#pragma unroll
    for (int i = 0; i < 4; ++i)
#pragma unroll
      for (int j = 0; j < 4; ++j)
        acc[i][j] = __builtin_amdgcn_mfma_f32_16x16x32_bf16(av[i], bv[j], acc[i][j], 0, 0, 0);
    __syncthreads();
  }

  const int orow = row0 + wr * 64 + (lane >> 4) * 4;
  const int ocol = col0 + wc * 64 + (lane & 15);
#pragma unroll
  for (int i = 0; i < 4; ++i)
#pragma unroll
    for (int j = 0; j < 4; ++j)
#pragma unroll
      for (int r = 0; r < 4; ++r)
        QKV[(size_t)(orow + i * 16 + r) * NQKV + ocol + j * 16] = f2bf(acc[i][j][r]);
}

// ---------------------------------------------------------------------------
// Causal flash attention attn9 (round-12 verified, unchanged).
// ---------------------------------------------------------------------------
__global__ __launch_bounds__(256, 2) void attn9(const unsigned short* __restrict__ QKV,
                                                float* __restrict__ Out) {
  __shared__ unsigned short sK [2][2][64 * 64];
  __shared__ unsigned short sVt[2][2][64 * 64];

  const int tid  = threadIdx.x;
  const int lane = tid & 63;
  const int wave = tid >> 6;
  const int l31  = lane & 31;
  const int hi   = lane >> 5;

  const int x = blockIdx.x;
  int bh, u;
  if (x < 256) { bh = x & 31; u = x >> 5; }
  else         { const int x2 = x - 256; bh = x2 & 31; u = 15 - (x2 >> 5); }

  const int b = bh >> 4, h = bh & 15;
  const int q0w  = u * 128 + wave * 32;
  const int qcol = q0w + l31;

  const unsigned short* Qbase = QKV + (size_t)(b * TOKENS) * NQKV + h * HDIM;
  const unsigned short* Kbase = Qbase + D_MODEL;
  const unsigned short* Vbase = Kbase + D_MODEL;

  bf16x8 qf[4];
  {
    const unsigned short* qrow = Qbase + (size_t)qcol * NQKV + hi * 8;
    union { unsigned short us[8]; bf16x8 v; ushort4 q[2]; } t;
#pragma unroll
    for (int dk = 0; dk < 4; ++dk) {
      t.q[0] = ((const ushort4*)(qrow + dk * 16))[0];
      t.q[1] = ((const ushort4*)(qrow + dk * 16))[1];
#pragma unroll
      for (int e = 0; e < 8; ++e) t.us[e] = f2bf(bf2f(t.us[e]) * SCALE);
      qf[dk] = t.v;
    }
  }

  f32x16 o0, o1;
#pragma unroll
  for (int r = 0; r < 16; ++r) { o0[r] = 0.f; o1[r] = 0.f; }
  float m = -1e30f, l = 0.f;

  const int vk0 = (tid & 15) * 4;
  const int vd0 = (tid >> 4) * 4;
  ushort4 va0, va1, va2, va3, vb0, vb1, vb2, vb3;

  const int lane16 = lane * 16;

#define KGLOAD(kt, buf, s)                                                     \
  {                                                                            \
    _Pragma("unroll")                                                          \
    for (int g = 0; g < 2; ++g) {                                              \
      const int base = g * 4096 + wave * 1024;                                 \
      const int d = base + lane16;                                             \
      const int row = d >> 7;                                                  \
      const int grow = (row & 51) | ((row & 4) << 1) | ((row & 8) >> 1);       \
      const int cb = (d & 127) ^ ((row & 7) << 4);                             \
      GLOAD16(Kbase + (size_t)((kt) * 64 + grow) * NQKV + (cb >> 1),           \
              (char*)&sK[buf][s][0] + base + lane16);                          \
    }                                                                          \
  }

#define VLOAD2(pp)                                                             \
  {                                                                            \
    const unsigned short* vsA = Vbase + (size_t)((2*(pp)) * 64 + vk0) * NQKV + vd0;   \
    va0 = *(const ushort4*)(vsA);                                              \
    va1 = *(const ushort4*)(vsA + NQKV);                                       \
    va2 = *(const ushort4*)(vsA + 2 * NQKV);                                   \
    va3 = *(const ushort4*)(vsA + 3 * NQKV);                                   \
    const unsigned short* vsB = Vbase + (size_t)((2*(pp)+1) * 64 + vk0) * NQKV + vd0; \
    vb0 = *(const ushort4*)(vsB);                                              \
    vb1 = *(const ushort4*)(vsB + NQKV);                                       \
    vb2 = *(const ushort4*)(vsB + 2 * NQKV);                                   \
    vb3 = *(const ushort4*)(vsB + 3 * NQKV);                                   \
  }

#define VWRITE1(buf, s, t0, t1, t2, t3)                                        \
  {                                                                            \
    ushort4 c0, c1, c2, c3;                                                    \
    c0.x = t0.x; c0.y = t1.x; c0.z = t2.x; c0.w = t3.x;                        \
    c1.x = t0.y; c1.y = t1.y; c1.z = t2.y; c1.w = t3.y;                        \
    c2.x = t0.z; c2.y = t1.z; c2.z = t2.z; c2.w = t3.z;                        \
    c3.x = t0.w; c3.y = t1.w; c3.z = t2.w; c3.w = t3.w;                        \
    char* dV = (char*)&sVt[buf][s][0];                                         \
    _Pragma("unroll")                                                          \
    for (int e = 0; e < 4; ++e) {                                              \
      const int dim = vd0 + e;                                                 \
      const int o2 = (dim * 128 + vk0 * 2) ^ ((dim & 7) << 4);                 \
      ushort4 cc = (e == 0) ? c0 : (e == 1) ? c1 : (e == 2) ? c2 : c3;         \
      *(ushort4*)(dV + o2) = cc;                                               \
    }                                                                          \
  }

#define QKT(cK, rowbase, st)                                                   \
  {                                                                            \
    _Pragma("unroll")                                                          \
    for (int dk = 0; dk < 4; ++dk) {                                           \
      const int row = (rowbase);                                               \
      bf16x8 kf = *(const bf16x8*)((cK) + ((row * 128 + hi * 16 + dk * 32) ^ ((row & 7) << 4))); \
      st = __builtin_amdgcn_mfma_f32_32x32x16_bf16(kf, qf[dk], st, 0, 0, 0);   \
    }                                                                          \
  }

#define PV4(cV, bpX, bpY, koff)                                                \
  {                                                                            \
    const int r0 = l31, r1 = l31 + 32;                                         \
    bf16x8 vf;                                                                 \
    vf = *(const bf16x8*)((cV) + ((r0 * 128 + hi * 16 + (koff)) ^ ((r0 & 7) << 4)));      \
    o0 = __builtin_amdgcn_mfma_f32_32x32x16_bf16(vf, bpX, o0, 0, 0, 0);        \
    vf = *(const bf16x8*)((cV) + ((r1 * 128 + hi * 16 + (koff)) ^ ((r1 & 7) << 4)));      \
    o1 = __builtin_amdgcn_mfma_f32_32x32x16_bf16(vf, bpX, o1, 0, 0, 0);        \
    vf = *(const bf16x8*)((cV) + ((r0 * 128 + hi * 16 + (koff) + 32) ^ ((r0 & 7) << 4))); \
    o0 = __builtin_amdgcn_mfma_f32_32x32x16_bf16(vf, bpY, o0, 0, 0, 0);        \
    vf = *(const bf16x8*)((cV) + ((r1 * 128 + hi * 16 + (koff) + 32) ^ ((r1 & 7) << 4))); \
    o1 = __builtin_amdgcn_mfma_f32_32x32x16_bf16(vf, bpY, o1, 0, 0, 0);        \
  }

  KGLOAD(0, 0, 0);
  KGLOAD(1, 0, 1);
  VLOAD2(0);
  VWRITE1(0, 0, va0, va1, va2, va3);
  VWRITE1(0, 1, vb0, vb1, vb2, vb3);
  __syncthreads();

#pragma unroll 1
  for (int p = 0; p < u; ++p) {
    const int cur = p & 1;
    KGLOAD(2 * (p + 1),     cur ^ 1, 0);
    KGLOAD(2 * (p + 1) + 1, cur ^ 1, 1);
    VLOAD2(p + 1);

    const char* cKA = (const char*)&sK[cur][0][0];
    const char* cKB = (const char*)&sK[cur][1][0];
    const char* cVA = (const char*)&sVt[cur][0][0];
    const char* cVB = (const char*)&sVt[cur][1][0];

    f32x16 sA0, sA1, sB0, sB1;
#pragma unroll
    for (int r = 0; r < 16; ++r) { sA0[r] = 0.f; sA1[r] = 0.f; sB0[r] = 0.f; sB1[r] = 0.f; }

    QKT(cKA, l31,      sA0);
    QKT(cKA, l31 + 32, sA1);
    QKT(cKB, l31,      sB0);
    QKT(cKB, l31 + 32, sB1);

    {
      float mx = max32t(sA0, sA1);
      mx = fmaxf(mx, xchg32(mx));
      if (!__all(mx - m <= 8.f)) {
        const float mnew = fmaxf(m, mx);
        const float corr = exp2f(m - mnew);
        m = mnew;
        l *= corr;
#pragma unroll
        for (int r = 0; r < 16; ++r) { o0[r] *= corr; o1[r] *= corr; }
      }
      float pA0[16], pA1[16];
#pragma unroll
      for (int r = 0; r < 16; ++r) { pA0[r] = exp2f(sA0[r] - m); pA1[r] = exp2f(sA1[r] - m); }
      float ps = sum32t(pA0, pA1);
      ps += xchg32(ps);
      l += ps;
      bf16x8 a0 = pfrag8(&pA0[0]), a1 = pfrag8(&pA0[8]);
      bf16x8 a2 = pfrag8(&pA1[0]), a3 = pfrag8(&pA1[8]);
      PV4(cVA, a0, a1, 0);
      PV4(cVA, a2, a3, 64);
    }

    {
      float mx = max32t(sB0, sB1);
      mx = fmaxf(mx, xchg32(mx));
      if (!__all(mx - m <= 8.f)) {
        const float mnew = fmaxf(m, mx);
        const float corr = exp2f(m - mnew);
        m = mnew;
        l *= corr;
#pragma unroll
        for (int r = 0; r < 16; ++r) { o0[r] *= corr; o1[r] *= corr; }
      }
      float pB0[16], pB1[16];
#pragma unroll
      for (int r = 0; r < 16; ++r) { pB0[r] = exp2f(sB0[r] - m); pB1[r] = exp2f(sB1[r] - m); }
      float ps = sum32t(pB0, pB1);
      ps += xchg32(ps);
      l += ps;
      bf16x8 b0 = pfrag8(&pB0[0]), b1 = pfrag8(&pB0[8]);
      bf16x8 b2 = pfrag8(&pB1[0]), b3 = pfrag8(&pB1[8]);
      PV4(cVB, b0, b1, 0);
      PV4(cVB, b2, b3, 64);
    }

    VWRITE1(cur ^ 1, 0, va0, va1, va2, va3);
    VWRITE1(cur ^ 1, 1, vb0, vb1, vb2, vb3);
    __syncthreads();
  }

  {
    const int cur = u & 1;
    const char* cK[2] = { (const char*)&sK[cur][0][0], (const char*)&sK[cur][1][0] };
    const char* cV[2] = { (const char*)&sVt[cur][0][0], (const char*)&sVt[cur][1][0] };
    const int nsub = (wave >= 2) ? 2 : 1;
#pragma unroll 1
    for (int s = 0; s < nsub; ++s) {
      const int kbase = u * 128 + s * 64;
      const bool diag  = (wave >= 2) ? (s == 1) : true;
      const bool do_hi = diag ? ((wave & 1) == 1) : true;

      f32x16 st0, st1;
#pragma unroll
      for (int r = 0; r < 16; ++r) { st0[r] = 0.f; st1[r] = 0.f; }

      QKT(cK[s], l31, st0);
      if (do_hi) QKT(cK[s], l31 + 32, st1);

      if (diag) {
#pragma unroll
        for (int r = 0; r < 16; ++r) {
          const int key0 = kbase + (r & 7) + ((r & 8) << 1) + 8 * hi;
          if (key0 > qcol) st0[r] = -1e30f;
          if (do_hi && key0 + 32 > qcol) st1[r] = -1e30f;
        }
      }

      float mx = do_hi ? max32t(st0, st1) : max32t(st0, st0);
      mx = fmaxf(mx, xchg32(mx));

      if (!__all(mx - m <= 8.f)) {
        const float mnew = fmaxf(m, mx);
        const float corr = exp2f(m - mnew);
        m = mnew;
        l *= corr;
#pragma unroll
        for (int r = 0; r < 16; ++r) { o0[r] *= corr; o1[r] *= corr; }
      }

      float p0[16], p1[16];
#pragma unroll
      for (int r = 0; r < 16; ++r) p0[r] = exp2f(st0[r] - m);
      float ps;
      if (do_hi) {
#pragma unroll
        for (int r = 0; r < 16; ++r) p1[r] = exp2f(st1[r] - m);
        ps = sum32t(p0, p1);
      } else {
        float z[16];
#pragma unroll
        for (int r = 0; r < 16; ++r) z[r] = 0.f;
        ps = sum32t(p0, z);
      }
      ps += xchg32(ps);
      l += ps;

      bf16x8 c0 = pfrag8(&p0[0]), c1 = pfrag8(&p0[8]);
      PV4(cV[s], c0, c1, 0);
      if (do_hi) {
        bf16x8 c2 = pfrag8(&p1[0]), c3 = pfrag8(&p1[8]);
        PV4(cV[s], c2, c3, 64);
      }
    }
  }

  {
    const float inv = 1.f / l;
    float* orow = Out + (size_t)(b * TOKENS + qcol) * D_MODEL + h * HDIM;
#pragma unroll
    for (int g = 0; g < 4; ++g) {
      float4 w0, w1;
      w0.x = o0[4*g+0] * inv; w0.y = o0[4*g+1] * inv;
      w0.z = o0[4*g+2] * inv; w0.w = o0[4*g+3] * inv;
      w1.x = o1[4*g+0] * inv; w1.y = o1[4*g+1] * inv;
      w1.z = o1[4*g+2] * inv; w1.w = o1[4*g+3] * inv;
      *(float4*)(orow + 8 * g + 4 * hi)      = w0;
      *(float4*)(orow + 8 * g + 4 * hi + 32) = w1;
    }
  }
}

extern "C" void kernel_launch(void* const* d_in, const int* in_sizes, int n_in,
                              void* d_out, int out_size, void* d_ws, size_t ws_size,
                              hipStream_t stream) {
  const float* X = (const float*)d_in[0];
  const float* W = (const float*)d_in[1];
  float* Out = (float*)d_out;
  unsigned short* QKV = (unsigned short*)d_ws;

  const size_t QKV_E = (size_t)MROWS * NQKV;
  const size_t XB_E  = (size_t)MROWS * D_MODEL;
  const size_t WB_E  = (size_t)NQKV * D_MODEL;
  const size_t need_bf16 = (QKV_E + XB_E + WB_E) * 2;

  if (ws_size >= need_bf16) {
    unsigned short* Xb = QKV + QKV_E;
    unsigned short* Wb = Xb + XB_E;
    cvt_bf16<<<(XB_E + WB_E) / (256 * 8), 256, 0, stream>>>(X, W, Xb, Wb);
    gemm8<<<dim3(MROWS / 256, NQKV / 256), 512, 0, stream>>>(Xb, Wb, QKV);
  } else {
    qkv_gemm<<<dim3(MROWS / 128, NQKV / 128), 256, 0, stream>>>(X, W, QKV);
  }

  attn9<<<512, 256, 0, stream>>>(QKV, Out);
}

// Round 17
// 99.385 us; speedup vs baseline: 1.5179x; 1.0240x over previous
//
#include <hip/hip_runtime.h>
#include <hip/hip_bf16.h>
#include <stdint.h>

#define D_MODEL 1024
#define TOKENS  2048
#define HEADS   16
#define HDIM    64
#define NQKV    3072      // 3*D_MODEL
#define MROWS   4096      // BATCH*TOKENS
#define SCALE   0.18033688011112042f   // 0.125 * log2(e)

typedef __attribute__((ext_vector_type(4)))  float f32x4;
typedef __attribute__((ext_vector_type(16))) float f32x16;
typedef __attribute__((ext_vector_type(8)))  short bf16x8;

__device__ __forceinline__ unsigned short f2bf(float f) {
  union { float f; unsigned u; } v; v.f = f;
  unsigned u = v.u + 0x7FFFu + ((v.u >> 16) & 1u);   // RNE
  return (unsigned short)(u >> 16);
}
__device__ __forceinline__ float bf2f(unsigned short b) {
  union { unsigned u; float f; } v; v.u = ((unsigned)b) << 16;
  return v.f;
}
__device__ __forceinline__ unsigned cvt_pk_bf16(float lo, float hi) {
  unsigned r;
  asm("v_cvt_pk_bf16_f32 %0, %1, %2" : "=v"(r) : "v"(lo), "v"(hi));
  return r;
}
__device__ __forceinline__ float xchg32(float v) {
  return __shfl_xor(v, 32);
}
__device__ __forceinline__ bf16x8 pfrag8(const float* g) {
  union { uint4 u; bf16x8 v; } r;
  r.u.x = cvt_pk_bf16(g[0], g[1]);
  r.u.y = cvt_pk_bf16(g[2], g[3]);
  r.u.z = cvt_pk_bf16(g[4], g[5]);
  r.u.w = cvt_pk_bf16(g[6], g[7]);
  return r.v;
}
__device__ __forceinline__ float max32t(const f32x16& a, const f32x16& b) {
  float t[16];
#pragma unroll
  for (int r = 0; r < 16; ++r) t[r] = fmaxf(a[r], b[r]);
#pragma unroll
  for (int s = 8; s > 0; s >>= 1)
#pragma unroll
    for (int r = 0; r < s; ++r) t[r] = fmaxf(t[r], t[r + s]);
  return t[0];
}
__device__ __forceinline__ float sum32t(const float* a, const float* b) {
  float t[16];
#pragma unroll
  for (int r = 0; r < 16; ++r) t[r] = a[r] + b[r];
#pragma unroll
  for (int s = 8; s > 0; s >>= 1)
#pragma unroll
    for (int r = 0; r < s; ++r) t[r] = t[r] + t[r + s];
  return t[0];
}

#define GLOAD16(g, l)                                                          \
  __builtin_amdgcn_global_load_lds(                                            \
      (const __attribute__((address_space(1))) unsigned int*)(g),              \
      (__attribute__((address_space(3))) unsigned int*)(l), 16, 0, 0)

// ---------------------------------------------------------------------------
// fp32 -> bf16 convert pass (X then W, contiguous).
// ---------------------------------------------------------------------------
__global__ __launch_bounds__(256) void cvt_bf16(const float* __restrict__ X,
                                                const float* __restrict__ W,
                                                unsigned short* __restrict__ Xb,
                                                unsigned short* __restrict__ Wb) {
  const size_t NX = (size_t)MROWS * D_MODEL;
  size_t i = ((size_t)blockIdx.x * 256 + threadIdx.x) * 8;
  const float* src; unsigned short* dst; size_t off;
  if (i < NX) { src = X; dst = Xb; off = i; }
  else        { src = W; dst = Wb; off = i - NX; }
  float4 a = ((const float4*)(src + off))[0];
  float4 b = ((const float4*)(src + off))[1];
  union { unsigned short s[8]; uint4 v; } u;
  u.s[0] = f2bf(a.x); u.s[1] = f2bf(a.y); u.s[2] = f2bf(a.z); u.s[3] = f2bf(a.w);
  u.s[4] = f2bf(b.x); u.s[5] = f2bf(b.y); u.s[6] = f2bf(b.z); u.s[7] = f2bf(b.w);
  *(uint4*)(dst + off) = u.v;
}

// ---------------------------------------------------------------------------
// 8-phase 256x256 GEMM, full (row&7)<<4 swizzle (round-15 verified), plus
// round-17 change: quadrant order (0,0),(0,1),(1,0),(1,1) with A-fragments
// HELD IN REGISTERS across the qn=0 -> qn=1 phase pair (A LDS reads halved;
// total LDS traffic -33% -> below the LDS-BW/MFMA balance point).
// Stage slots / vmcnt placement / barriers identical to the verified version.
// ---------------------------------------------------------------------------
__global__ __launch_bounds__(512, 1) void gemm8(const unsigned short* __restrict__ A,
                                                const unsigned short* __restrict__ B,
                                                unsigned short* __restrict__ C) {
  __shared__ unsigned short sA[2][2][128][64];
  __shared__ unsigned short sB[2][2][128][64];

  const int tid  = threadIdx.x;
  const int lane = tid & 63;
  const int wave = tid >> 6;
  const int wr   = wave >> 2;
  const int wc   = wave & 3;
  const int l15  = lane & 15;
  const int lg   = lane >> 4;

  const int bm = blockIdx.x;
  const int bn = blockIdx.y;

  f32x4 acc[8][4];
#pragma unroll
  for (int i = 0; i < 8; ++i)
#pragma unroll
    for (int j = 0; j < 4; ++j)
#pragma unroll
      for (int r = 0; r < 4; ++r) acc[i][j][r] = 0.f;

  const int srow = tid >> 3;
  const int scb  = (tid & 7) * 16;
  const int ssce = (scb ^ ((srow & 7) << 4)) >> 1;

  const unsigned short* Ag = A + (size_t)(bm * 256) * D_MODEL;
  const unsigned short* Bg = B + (size_t)(bn * 256) * D_MODEL;

#define STG_A(buf, hf, t)                                                      \
  { GLOAD16(Ag + (size_t)((hf) * 128 + srow) * D_MODEL + (t) * 64 + ssce,      \
            (char*)&sA[buf][hf][0][0] + srow * 128 + scb);                     \
    GLOAD16(Ag + (size_t)((hf) * 128 + 64 + srow) * D_MODEL + (t) * 64 + ssce, \
            (char*)&sA[buf][hf][0][0] + 8192 + srow * 128 + scb); }
#define STG_B(buf, hf, t)                                                      \
  { GLOAD16(Bg + (size_t)((hf) * 128 + srow) * D_MODEL + (t) * 64 + ssce,      \
            (char*)&sB[buf][hf][0][0] + srow * 128 + scb);                     \
    GLOAD16(Bg + (size_t)((hf) * 128 + 64 + srow) * D_MODEL + (t) * 64 + ssce, \
            (char*)&sB[buf][hf][0][0] + 8192 + srow * 128 + scb); }

  const char* aBse[2] = { (const char*)&sA[0][wr][0][0], (const char*)&sA[1][wr][0][0] };
  const char* bBse[2] = { (const char*)&sB[0][wc >> 1][0][0], (const char*)&sB[1][wc >> 1][0][0] };
  const int swzl = (l15 & 7) << 4;
  const int cbs0 = (lg * 16) ^ swzl;
  const int cbs1 = (64 + lg * 16) ^ swzl;
  const int arow = l15 * 128;
  const int brow = ((wc & 1) * 64 + l15) * 128;

  bf16x8 aF[4][2];    // A-fragments held across the qn=0 -> qn=1 phase pair

// LD_A==1: read A-frags for quadrant qm into aF; LD_A==0: reuse aF.
#define DO_PHASE(qm, qn, buf, LD_A, STAGE_STMT, DO_VM)                         \
  {                                                                            \
    if (LD_A) {                                                                \
      _Pragma("unroll")                                                        \
      for (int i = 0; i < 4; ++i) {                                            \
        aF[i][0] = *(const bf16x8*)(aBse[buf] + ((qm)*4 + i) * 2048 + arow + cbs0); \
        aF[i][1] = *(const bf16x8*)(aBse[buf] + ((qm)*4 + i) * 2048 + arow + cbs1); \
      }                                                                        \
    }                                                                          \
    bf16x8 b_[2][2];                                                           \
    _Pragma("unroll")                                                          \
    for (int n = 0; n < 2; ++n) {                                              \
      b_[n][0] = *(const bf16x8*)(bBse[buf] + ((qn)*2 + n) * 2048 + brow + cbs0); \
      b_[n][1] = *(const bf16x8*)(bBse[buf] + ((qn)*2 + n) * 2048 + brow + cbs1); \
    }                                                                          \
    STAGE_STMT;                                                                \
    if (DO_VM) asm volatile("s_waitcnt vmcnt(2)" ::: "memory");                \
    __builtin_amdgcn_s_barrier();                                              \
    asm volatile("s_waitcnt lgkmcnt(0)" ::: "memory");                         \
    __builtin_amdgcn_sched_barrier(0);                                         \
    __builtin_amdgcn_s_setprio(1);                                             \
    _Pragma("unroll")                                                          \
    for (int ks = 0; ks < 2; ++ks)                                             \
      _Pragma("unroll")                                                        \
      for (int i = 0; i < 4; ++i)                                              \
        _Pragma("unroll")                                                      \
        for (int n = 0; n < 2; ++n)                                            \
          acc[(qm)*4 + i][(qn)*2 + n] = __builtin_amdgcn_mfma_f32_16x16x32_bf16( \
              aF[i][ks], b_[n][ks], acc[(qm)*4 + i][(qn)*2 + n], 0, 0, 0);     \
    __builtin_amdgcn_s_setprio(0);                                             \
    __builtin_amdgcn_s_barrier();                                              \
  }

  STG_A(0, 0, 0);
  STG_B(0, 0, 0);
  STG_A(0, 1, 0);
  STG_B(0, 1, 0);
  STG_B(1, 0, 1);
  asm volatile("s_waitcnt vmcnt(2)" ::: "memory");
  __builtin_amdgcn_s_barrier();

#pragma unroll 1
  for (int j = 0; j < 8; ++j) {
    const int t1 = 2 * j + 1;
    const int t2 = 2 * j + 2;
    const int t3 = 2 * j + 3;
    // window 0: tile 2j (buf0); quadrants (0,0),(0,1),(1,0),(1,1)
    DO_PHASE(0, 0, 0, 1, { STG_A(1, 0, t1); }, 0);
    DO_PHASE(0, 1, 0, 0, { STG_A(1, 1, t1); }, 0);
    DO_PHASE(1, 0, 0, 1, { STG_B(1, 1, t1); }, 0);
    DO_PHASE(1, 1, 0, 0, { if (t2 < 16) STG_B(0, 0, t2); }, 1);
    // window 1: tile 2j+1 (buf1)
    DO_PHASE(0, 0, 1, 1, { if (t2 < 16) STG_A(0, 0, t2); }, 0);
    DO_PHASE(0, 1, 1, 0, { if (t2 < 16) STG_A(0, 1, t2); }, 0);
    DO_PHASE(1, 0, 1, 1, { if (t2 < 16) STG_B(0, 1, t2); }, 0);
    DO_PHASE(1, 1, 1, 0, { if (t3 < 16) STG_B(1, 0, t3); }, 1);
  }

  const int orow0 = bm * 256 + wr * 128 + lg * 4;
  const int ocol0 = bn * 256 + wc * 64 + l15;
#pragma unroll
  for (int mi = 0; mi < 8; ++mi)
#pragma unroll
    for (int ni = 0; ni < 4; ++ni)
#pragma unroll
      for (int r = 0; r < 4; ++r)
        C[(size_t)(orow0 + mi * 16 + r) * NQKV + ocol0 + ni * 16] = f2bf(acc[mi][ni][r]);
#undef STG_A
#undef STG_B
#undef DO_PHASE
}

// ---------------------------------------------------------------------------
// Fallback fp32-input GEMM for small ws (round-1 verified).
// ---------------------------------------------------------------------------
__global__ __launch_bounds__(256) void qkv_gemm(const float* __restrict__ X,
                                                const float* __restrict__ W,
                                                unsigned short* __restrict__ QKV) {
  __shared__ unsigned short sA[128 * 32];
  __shared__ unsigned short sB[128 * 32];
  const int tid  = threadIdx.x;
  const int lane = tid & 63;
  const int wave = tid >> 6;
  const int wr = wave >> 1, wc = wave & 1;
  const int row0 = blockIdx.x * 128;
  const int col0 = blockIdx.y * 128;

  f32x4 acc[4][4];
#pragma unroll
  for (int i = 0; i < 4; ++i)
#pragma unroll
    for (int j = 0; j < 4; ++j)
#pragma unroll
      for (int r = 0; r < 4; ++r) acc[i][j][r] = 0.f;

  const int srow = tid >> 1;
  const int scol = (tid & 1) * 16;
  union U16 { unsigned short s[8]; uint4 v; };

#pragma unroll 1
  for (int k0 = 0; k0 < D_MODEL; k0 += 32) {
    {
      const float* ga = X + (size_t)(row0 + srow) * D_MODEL + k0 + scol;
      const float* gb = W + (size_t)(col0 + srow) * D_MODEL + k0 + scol;
      float va[16], vb[16];
#pragma unroll
      for (int i = 0; i < 4; ++i) {
        float4 t = ((const float4*)ga)[i];
        va[4*i+0] = t.x; va[4*i+1] = t.y; va[4*i+2] = t.z; va[4*i+3] = t.w;
        float4 u = ((const float4*)gb)[i];
        vb[4*i+0] = u.x; vb[4*i+1] = u.y; vb[4*i+2] = u.z; vb[4*i+3] = u.w;
      }
      U16 ua0, ua1, ub0, ub1;
#pragma unroll
      for (int e = 0; e < 8; ++e) {
        ua0.s[e] = f2bf(va[e]);   ua1.s[e] = f2bf(va[8 + e]);
        ub0.s[e] = f2bf(vb[e]);   ub1.s[e] = f2bf(vb[8 + e]);
      }
      *(uint4*)&sA[srow * 32 + scol + 0] = ua0.v;
      *(uint4*)&sA[srow * 32 + scol + 8] = ua1.v;
      *(uint4*)&sB[srow * 32 + scol + 0] = ub0.v;
      *(uint4*)&sB[srow * 32 + scol + 8] = ub1.v;
    }
    __syncthreads();

    const int lrow = lane & 15;
    const int lk   = (lane >> 4) * 8;
    bf16x8 av[4], bv[4];
#pragma unroll
    for (int i = 0; i < 4; ++i)
      av[i] = *(const bf16x8*)&sA[(wr * 64 + i * 16 + lrow) * 32 + lk];
#pragma unroll
    for (int j = 0; j < 4; ++j)
      bv[j] = *(const bf16x8*)&sB[(wc * 64 + j * 16 + lrow) * 32 + lk];
#pragma unroll
    for (int i = 0; i < 4; ++i)
#pragma unroll
      for (int j = 0; j < 4; ++j)
        acc[i][j] = __builtin_amdgcn_mfma_f32_16x16x32_bf16(av[i], bv[j], acc[i][j], 0, 0, 0);
    __syncthreads();
  }

  const int orow = row0 + wr * 64 + (lane >> 4) * 4;
  const int ocol = col0 + wc * 64 + (lane & 15);
#pragma unroll
  for (int i = 0; i < 4; ++i)
#pragma unroll
    for (int j = 0; j < 4; ++j)
#pragma unroll
      for (int r = 0; r < 4; ++r)
        QKV[(size_t)(orow + i * 16 + r) * NQKV + ocol + j * 16] = f2bf(acc[i][j][r]);
}

// ---------------------------------------------------------------------------
// Causal flash attention attn9 (round-12 verified, unchanged).
// ---------------------------------------------------------------------------
__global__ __launch_bounds__(256, 2) void attn9(const unsigned short* __restrict__ QKV,
                                                float* __restrict__ Out) {
  __shared__ unsigned short sK [2][2][64 * 64];
  __shared__ unsigned short sVt[2][2][64 * 64];

  const int tid  = threadIdx.x;
  const int lane = tid & 63;
  const int wave = tid >> 6;
  const int l31  = lane & 31;
  const int hi   = lane >> 5;

  const int x = blockIdx.x;
  int bh, u;
  if (x < 256) { bh = x & 31; u = x >> 5; }
  else         { const int x2 = x - 256; bh = x2 & 31; u = 15 - (x2 >> 5); }

  const int b = bh >> 4, h = bh & 15;
  const int q0w  = u * 128 + wave * 32;
  const int qcol = q0w + l31;

  const unsigned short* Qbase = QKV + (size_t)(b * TOKENS) * NQKV + h * HDIM;
  const unsigned short* Kbase = Qbase + D_MODEL;
  const unsigned short* Vbase = Kbase + D_MODEL;

  bf16x8 qf[4];
  {
    const unsigned short* qrow = Qbase + (size_t)qcol * NQKV + hi * 8;
    union { unsigned short us[8]; bf16x8 v; ushort4 q[2]; } t;
#pragma unroll
    for (int dk = 0; dk < 4; ++dk) {
      t.q[0] = ((const ushort4*)(qrow + dk * 16))[0];
      t.q[1] = ((const ushort4*)(qrow + dk * 16))[1];
#pragma unroll
      for (int e = 0; e < 8; ++e) t.us[e] = f2bf(bf2f(t.us[e]) * SCALE);
      qf[dk] = t.v;
    }
  }

  f32x16 o0, o1;
#pragma unroll
  for (int r = 0; r < 16; ++r) { o0[r] = 0.f; o1[r] = 0.f; }
  float m = -1e30f, l = 0.f;

  const int vk0 = (tid & 15) * 4;
  const int vd0 = (tid >> 4) * 4;
  ushort4 va0, va1, va2, va3, vb0, vb1, vb2, vb3;

  const int lane16 = lane * 16;

#define KGLOAD(kt, buf, s)                                                     \
  {                                                                            \
    _Pragma("unroll")                                                          \
    for (int g = 0; g < 2; ++g) {                                              \
      const int base = g * 4096 + wave * 1024;                                 \
      const int d = base + lane16;                                             \
      const int row = d >> 7;                                                  \
      const int grow = (row & 51) | ((row & 4) << 1) | ((row & 8) >> 1);       \
      const int cb = (d & 127) ^ ((row & 7) << 4);                             \
      GLOAD16(Kbase + (size_t)((kt) * 64 + grow) * NQKV + (cb >> 1),           \
              (char*)&sK[buf][s][0] + base + lane16);                          \
    }                                                                          \
  }

#define VLOAD2(pp)                                                             \
  {                                                                            \
    const unsigned short* vsA = Vbase + (size_t)((2*(pp)) * 64 + vk0) * NQKV + vd0;   \
    va0 = *(const ushort4*)(vsA);                                              \
    va1 = *(const ushort4*)(vsA + NQKV);                                       \
    va2 = *(const ushort4*)(vsA + 2 * NQKV);                                   \
    va3 = *(const ushort4*)(vsA + 3 * NQKV);                                   \
    const unsigned short* vsB = Vbase + (size_t)((2*(pp)+1) * 64 + vk0) * NQKV + vd0; \
    vb0 = *(const ushort4*)(vsB);                                              \
    vb1 = *(const ushort4*)(vsB + NQKV);                                       \
    vb2 = *(const ushort4*)(vsB + 2 * NQKV);                                   \
    vb3 = *(const ushort4*)(vsB + 3 * NQKV);                                   \
  }

#define VWRITE1(buf, s, t0, t1, t2, t3)                                        \
  {                                                                            \
    ushort4 c0, c1, c2, c3;                                                    \
    c0.x = t0.x; c0.y = t1.x; c0.z = t2.x; c0.w = t3.x;                        \
    c1.x = t0.y; c1.y = t1.y; c1.z = t2.y; c1.w = t3.y;                        \
    c2.x = t0.z; c2.y = t1.z; c2.z = t2.z; c2.w = t3.z;                        \
    c3.x = t0.w; c3.y = t1.w; c3.z = t2.w; c3.w = t3.w;                        \
    char* dV = (char*)&sVt[buf][s][0];                                         \
    _Pragma("unroll")                                                          \
    for (int e = 0; e < 4; ++e) {                                              \
      const int dim = vd0 + e;                                                 \
      const int o2 = (dim * 128 + vk0 * 2) ^ ((dim & 7) << 4);                 \
      ushort4 cc = (e == 0) ? c0 : (e == 1) ? c1 : (e == 2) ? c2 : c3;         \
      *(ushort4*)(dV + o2) = cc;                                               \
    }                                                                          \
  }

#define QKT(cK, rowbase, st)                                                   \
  {                                                                            \
    _Pragma("unroll")                                                          \
    for (int dk = 0; dk < 4; ++dk) {                                           \
      const int row = (rowbase);                                               \
      bf16x8 kf = *(const bf16x8*)((cK) + ((row * 128 + hi * 16 + dk * 32) ^ ((row & 7) << 4))); \
      st = __builtin_amdgcn_mfma_f32_32x32x16_bf16(kf, qf[dk], st, 0, 0, 0);   \
    }                                                                          \
  }

#define PV4(cV, bpX, bpY, koff)                                                \
  {                                                                            \
    const int r0 = l31, r1 = l31 + 32;                                         \
    bf16x8 vf;                                                                 \
    vf = *(const bf16x8*)((cV) + ((r0 * 128 + hi * 16 + (koff)) ^ ((r0 & 7) << 4)));      \
    o0 = __builtin_amdgcn_mfma_f32_32x32x16_bf16(vf, bpX, o0, 0, 0, 0);        \
    vf = *(const bf16x8*)((cV) + ((r1 * 128 + hi * 16 + (koff)) ^ ((r1 & 7) << 4)));      \
    o1 = __builtin_amdgcn_mfma_f32_32x32x16_bf16(vf, bpX, o1, 0, 0, 0);        \
    vf = *(const bf16x8*)((cV) + ((r0 * 128 + hi * 16 + (koff) + 32) ^ ((r0 & 7) << 4))); \
    o0 = __builtin_amdgcn_mfma_f32_32x32x16_bf16(vf, bpY, o0, 0, 0, 0);        \
    vf = *(const bf16x8*)((cV) + ((r1 * 128 + hi * 16 + (koff) + 32) ^ ((r1 & 7) << 4))); \
    o1 = __builtin_amdgcn_mfma_f32_32x32x16_bf16(vf, bpY, o1, 0, 0, 0);        \
  }

  KGLOAD(0, 0, 0);
  KGLOAD(1, 0, 1);
  VLOAD2(0);
  VWRITE1(0, 0, va0, va1, va2, va3);
  VWRITE1(0, 1, vb0, vb1, vb2, vb3);
  __syncthreads();

#pragma unroll 1
  for (int p = 0; p < u; ++p) {
    const int cur = p & 1;
    KGLOAD(2 * (p + 1),     cur ^ 1, 0);
    KGLOAD(2 * (p + 1) + 1, cur ^ 1, 1);
    VLOAD2(p + 1);

    const char* cKA = (const char*)&sK[cur][0][0];
    const char* cKB = (const char*)&sK[cur][1][0];
    const char* cVA = (const char*)&sVt[cur][0][0];
    const char* cVB = (const char*)&sVt[cur][1][0];

    f32x16 sA0, sA1, sB0, sB1;
#pragma unroll
    for (int r = 0; r < 16; ++r) { sA0[r] = 0.f; sA1[r] = 0.f; sB0[r] = 0.f; sB1[r] = 0.f; }

    QKT(cKA, l31,      sA0);
    QKT(cKA, l31 + 32, sA1);
    QKT(cKB, l31,      sB0);
    QKT(cKB, l31 + 32, sB1);

    {
      float mx = max32t(sA0, sA1);
      mx = fmaxf(mx, xchg32(mx));
      if (!__all(mx - m <= 8.f)) {
        const float mnew = fmaxf(m, mx);
        const float corr = exp2f(m - mnew);
        m = mnew;
        l *= corr;
#pragma unroll
        for (int r = 0; r < 16; ++r) { o0[r] *= corr; o1[r] *= corr; }
      }
      float pA0[16], pA1[16];
#pragma unroll
      for (int r = 0; r < 16; ++r) { pA0[r] = exp2f(sA0[r] - m); pA1[r] = exp2f(sA1[r] - m); }
      float ps = sum32t(pA0, pA1);
      ps += xchg32(ps);
      l += ps;
      bf16x8 a0 = pfrag8(&pA0[0]), a1 = pfrag8(&pA0[8]);
      bf16x8 a2 = pfrag8(&pA1[0]), a3 = pfrag8(&pA1[8]);
      PV4(cVA, a0, a1, 0);
      PV4(cVA, a2, a3, 64);
    }

    {
      float mx = max32t(sB0, sB1);
      mx = fmaxf(mx, xchg32(mx));
      if (!__all(mx - m <= 8.f)) {
        const float mnew = fmaxf(m, mx);
        const float corr = exp2f(m - mnew);
        m = mnew;
        l *= corr;
#pragma unroll
        for (int r = 0; r < 16; ++r) { o0[r] *= corr; o1[r] *= corr; }
      }
      float pB0[16], pB1[16];
#pragma unroll
      for (int r = 0; r < 16; ++r) { pB0[r] = exp2f(sB0[r] - m); pB1[r] = exp2f(sB1[r] - m); }
      float ps = sum32t(pB0, pB1);
      ps += xchg32(ps);
      l += ps;
      bf16x8 b0 = pfrag8(&pB0[0]), b1 = pfrag8(&pB0[8]);
      bf16x8 b2 = pfrag8(&pB1[0]), b3 = pfrag8(&pB1[8]);
      PV4(cVB, b0, b1, 0);
      PV4(cVB, b2, b3, 64);
    }

    VWRITE1(cur ^ 1, 0, va0, va1, va2, va3);
    VWRITE1(cur ^ 1, 1, vb0, vb1, vb2, vb3);
    __syncthreads();
  }

  {
    const int cur = u & 1;
    const char* cK[2] = { (const char*)&sK[cur][0][0], (const char*)&sK[cur][1][0] };
    const char* cV[2] = { (const char*)&sVt[cur][0][0], (const char*)&sVt[cur][1][0] };
    const int nsub = (wave >= 2) ? 2 : 1;
#pragma unroll 1
    for (int s = 0; s < nsub; ++s) {
      const int kbase = u * 128 + s * 64;
      const bool diag  = (wave >= 2) ? (s == 1) : true;
      const bool do_hi = diag ? ((wave & 1) == 1) : true;

      f32x16 st0, st1;
#pragma unroll
      for (int r = 0; r < 16; ++r) { st0[r] = 0.f; st1[r] = 0.f; }

      QKT(cK[s], l31, st0);
      if (do_hi) QKT(cK[s], l31 + 32, st1);

      if (diag) {
#pragma unroll
        for (int r = 0; r < 16; ++r) {
          const int key0 = kbase + (r & 7) + ((r & 8) << 1) + 8 * hi;
          if (key0 > qcol) st0[r] = -1e30f;
          if (do_hi && key0 + 32 > qcol) st1[r] = -1e30f;
        }
      }

      float mx = do_hi ? max32t(st0, st1) : max32t(st0, st0);
      mx = fmaxf(mx, xchg32(mx));

      if (!__all(mx - m <= 8.f)) {
        const float mnew = fmaxf(m, mx);
        const float corr = exp2f(m - mnew);
        m = mnew;
        l *= corr;
#pragma unroll
        for (int r = 0; r < 16; ++r) { o0[r] *= corr; o1[r] *= corr; }
      }

      float p0[16], p1[16];
#pragma unroll
      for (int r = 0; r < 16; ++r) p0[r] = exp2f(st0[r] - m);
      float ps;
      if (do_hi) {
#pragma unroll
        for (int r = 0; r < 16; ++r) p1[r] = exp2f(st1[r] - m);
        ps = sum32t(p0, p1);
      } else {
        float z[16];
#pragma unroll
        for (int r = 0; r < 16; ++r) z[r] = 0.f;
        ps = sum32t(p0, z);
      }
      ps += xchg32(ps);
      l += ps;

      bf16x8 c0 = pfrag8(&p0[0]), c1 = pfrag8(&p0[8]);
      PV4(cV[s], c0, c1, 0);
      if (do_hi) {
        bf16x8 c2 = pfrag8(&p1[0]), c3 = pfrag8(&p1[8]);
        PV4(cV[s], c2, c3, 64);
      }
    }
  }

  {
    const float inv = 1.f / l;
    float* orow = Out + (size_t)(b * TOKENS + qcol) * D_MODEL + h * HDIM;
#pragma unroll
    for (int g = 0; g < 4; ++g) {
      float4 w0, w1;
      w0.x = o0[4*g+0] * inv; w0.y = o0[4*g+1] * inv;
      w0.z = o0[4*g+2] * inv; w0.w = o0[4*g+3] * inv;
      w1.x = o1[4*g+0] * inv; w1.y = o1[4*g+1] * inv;
      w1.z = o1[4*g+2] * inv; w1.w = o1[4*g+3] * inv;
      *(float4*)(orow + 8 * g + 4 * hi)      = w0;
      *(float4*)(orow + 8 * g + 4 * hi + 32) = w1;
    }
  }
}

extern "C" void kernel_launch(void* const* d_in, const int* in_sizes, int n_in,
                              void* d_out, int out_size, void* d_ws, size_t ws_size,
                              hipStream_t stream) {
  const float* X = (const float*)d_in[0];
  const float* W = (const float*)d_in[1];
  float* Out = (float*)d_out;
  unsigned short* QKV = (unsigned short*)d_ws;

  const size_t QKV_E = (size_t)MROWS * NQKV;
  const size_t XB_E  = (size_t)MROWS * D_MODEL;
  const size_t WB_E  = (size_t)NQKV * D_MODEL;
  const size_t need_bf16 = (QKV_E + XB_E + WB_E) * 2;

  if (ws_size >= need_bf16) {
    unsigned short* Xb = QKV + QKV_E;
    unsigned short* Wb = Xb + XB_E;
    cvt_bf16<<<(XB_E + WB_E) / (256 * 8), 256, 0, stream>>>(X, W, Xb, Wb);
    gemm8<<<dim3(MROWS / 256, NQKV / 256), 512, 0, stream>>>(Xb, Wb, QKV);
  } else {
    qkv_gemm<<<dim3(MROWS / 128, NQKV / 128), 256, 0, stream>>>(X, W, QKV);
  }

  attn9<<<512, 256, 0, stream>>>(QKV, Out);
}

// Round 18
// 98.291 us; speedup vs baseline: 1.5348x; 1.0111x over previous
//
#include <hip/hip_runtime.h>
#include <hip/hip_bf16.h>
#include <stdint.h>

#define D_MODEL 1024
#define TOKENS  2048
#define HEADS   16
#define HDIM    64
#define NQKV    3072      // 3*D_MODEL
#define MROWS   4096      // BATCH*TOKENS
#define SCALE   0.18033688011112042f   // 0.125 * log2(e)

typedef __attribute__((ext_vector_type(4)))  float f32x4;
typedef __attribute__((ext_vector_type(16))) float f32x16;
typedef __attribute__((ext_vector_type(8)))  short bf16x8;

__device__ __forceinline__ unsigned short f2bf(float f) {
  union { float f; unsigned u; } v; v.f = f;
  unsigned u = v.u + 0x7FFFu + ((v.u >> 16) & 1u);   // RNE
  return (unsigned short)(u >> 16);
}
__device__ __forceinline__ float bf2f(unsigned short b) {
  union { unsigned u; float f; } v; v.u = ((unsigned)b) << 16;
  return v.f;
}
__device__ __forceinline__ unsigned cvt_pk_bf16(float lo, float hi) {
  unsigned r;
  asm("v_cvt_pk_bf16_f32 %0, %1, %2" : "=v"(r) : "v"(lo), "v"(hi));
  return r;
}
__device__ __forceinline__ float xchg32(float v) {
  return __shfl_xor(v, 32);
}
__device__ __forceinline__ bf16x8 pfrag8(const float* g) {
  union { uint4 u; bf16x8 v; } r;
  r.u.x = cvt_pk_bf16(g[0], g[1]);
  r.u.y = cvt_pk_bf16(g[2], g[3]);
  r.u.z = cvt_pk_bf16(g[4], g[5]);
  r.u.w = cvt_pk_bf16(g[6], g[7]);
  return r.v;
}
__device__ __forceinline__ float max32t(const f32x16& a, const f32x16& b) {
  float t[16];
#pragma unroll
  for (int r = 0; r < 16; ++r) t[r] = fmaxf(a[r], b[r]);
#pragma unroll
  for (int s = 8; s > 0; s >>= 1)
#pragma unroll
    for (int r = 0; r < s; ++r) t[r] = fmaxf(t[r], t[r + s]);
  return t[0];
}
__device__ __forceinline__ float sum32t(const float* a, const float* b) {
  float t[16];
#pragma unroll
  for (int r = 0; r < 16; ++r) t[r] = a[r] + b[r];
#pragma unroll
  for (int s = 8; s > 0; s >>= 1)
#pragma unroll
    for (int r = 0; r < s; ++r) t[r] = t[r] + t[r + s];
  return t[0];
}

#define GLOAD16(g, l)                                                          \
  __builtin_amdgcn_global_load_lds(                                            \
      (const __attribute__((address_space(1))) unsigned int*)(g),              \
      (__attribute__((address_space(3))) unsigned int*)(l), 16, 0, 0)

// ---------------------------------------------------------------------------
// fp32 -> bf16 convert pass (X then W, contiguous).
// ---------------------------------------------------------------------------
__global__ __launch_bounds__(256) void cvt_bf16(const float* __restrict__ X,
                                                const float* __restrict__ W,
                                                unsigned short* __restrict__ Xb,
                                                unsigned short* __restrict__ Wb) {
  const size_t NX = (size_t)MROWS * D_MODEL;
  size_t i = ((size_t)blockIdx.x * 256 + threadIdx.x) * 8;
  const float* src; unsigned short* dst; size_t off;
  if (i < NX) { src = X; dst = Xb; off = i; }
  else        { src = W; dst = Wb; off = i - NX; }
  float4 a = ((const float4*)(src + off))[0];
  float4 b = ((const float4*)(src + off))[1];
  union { unsigned short s[8]; uint4 v; } u;
  u.s[0] = f2bf(a.x); u.s[1] = f2bf(a.y); u.s[2] = f2bf(a.z); u.s[3] = f2bf(a.w);
  u.s[4] = f2bf(b.x); u.s[5] = f2bf(b.y); u.s[6] = f2bf(b.z); u.s[7] = f2bf(b.w);
  *(uint4*)(dst + off) = u.v;
}

// ---------------------------------------------------------------------------
// 8-phase 256x256 GEMM (round-17 verified: full swizzle + A-frag reuse).
// ---------------------------------------------------------------------------
__global__ __launch_bounds__(512, 1) void gemm8(const unsigned short* __restrict__ A,
                                                const unsigned short* __restrict__ B,
                                                unsigned short* __restrict__ C) {
  __shared__ unsigned short sA[2][2][128][64];
  __shared__ unsigned short sB[2][2][128][64];

  const int tid  = threadIdx.x;
  const int lane = tid & 63;
  const int wave = tid >> 6;
  const int wr   = wave >> 2;
  const int wc   = wave & 3;
  const int l15  = lane & 15;
  const int lg   = lane >> 4;

  const int bm = blockIdx.x;
  const int bn = blockIdx.y;

  f32x4 acc[8][4];
#pragma unroll
  for (int i = 0; i < 8; ++i)
#pragma unroll
    for (int j = 0; j < 4; ++j)
#pragma unroll
      for (int r = 0; r < 4; ++r) acc[i][j][r] = 0.f;

  const int srow = tid >> 3;
  const int scb  = (tid & 7) * 16;
  const int ssce = (scb ^ ((srow & 7) << 4)) >> 1;

  const unsigned short* Ag = A + (size_t)(bm * 256) * D_MODEL;
  const unsigned short* Bg = B + (size_t)(bn * 256) * D_MODEL;

#define STG_A(buf, hf, t)                                                      \
  { GLOAD16(Ag + (size_t)((hf) * 128 + srow) * D_MODEL + (t) * 64 + ssce,      \
            (char*)&sA[buf][hf][0][0] + srow * 128 + scb);                     \
    GLOAD16(Ag + (size_t)((hf) * 128 + 64 + srow) * D_MODEL + (t) * 64 + ssce, \
            (char*)&sA[buf][hf][0][0] + 8192 + srow * 128 + scb); }
#define STG_B(buf, hf, t)                                                      \
  { GLOAD16(Bg + (size_t)((hf) * 128 + srow) * D_MODEL + (t) * 64 + ssce,      \
            (char*)&sB[buf][hf][0][0] + srow * 128 + scb);                     \
    GLOAD16(Bg + (size_t)((hf) * 128 + 64 + srow) * D_MODEL + (t) * 64 + ssce, \
            (char*)&sB[buf][hf][0][0] + 8192 + srow * 128 + scb); }

  const char* aBse[2] = { (const char*)&sA[0][wr][0][0], (const char*)&sA[1][wr][0][0] };
  const char* bBse[2] = { (const char*)&sB[0][wc >> 1][0][0], (const char*)&sB[1][wc >> 1][0][0] };
  const int swzl = (l15 & 7) << 4;
  const int cbs0 = (lg * 16) ^ swzl;
  const int cbs1 = (64 + lg * 16) ^ swzl;
  const int arow = l15 * 128;
  const int brow = ((wc & 1) * 64 + l15) * 128;

  bf16x8 aF[4][2];

#define DO_PHASE(qm, qn, buf, LD_A, STAGE_STMT, DO_VM)                         \
  {                                                                            \
    if (LD_A) {                                                                \
      _Pragma("unroll")                                                        \
      for (int i = 0; i < 4; ++i) {                                            \
        aF[i][0] = *(const bf16x8*)(aBse[buf] + ((qm)*4 + i) * 2048 + arow + cbs0); \
        aF[i][1] = *(const bf16x8*)(aBse[buf] + ((qm)*4 + i) * 2048 + arow + cbs1); \
      }                                                                        \
    }                                                                          \
    bf16x8 b_[2][2];                                                           \
    _Pragma("unroll")                                                          \
    for (int n = 0; n < 2; ++n) {                                              \
      b_[n][0] = *(const bf16x8*)(bBse[buf] + ((qn)*2 + n) * 2048 + brow + cbs0); \
      b_[n][1] = *(const bf16x8*)(bBse[buf] + ((qn)*2 + n) * 2048 + brow + cbs1); \
    }                                                                          \
    STAGE_STMT;                                                                \
    if (DO_VM) asm volatile("s_waitcnt vmcnt(2)" ::: "memory");                \
    __builtin_amdgcn_s_barrier();                                              \
    asm volatile("s_waitcnt lgkmcnt(0)" ::: "memory");                         \
    __builtin_amdgcn_sched_barrier(0);                                         \
    __builtin_amdgcn_s_setprio(1);                                             \
    _Pragma("unroll")                                                          \
    for (int ks = 0; ks < 2; ++ks)                                             \
      _Pragma("unroll")                                                        \
      for (int i = 0; i < 4; ++i)                                              \
        _Pragma("unroll")                                                      \
        for (int n = 0; n < 2; ++n)                                            \
          acc[(qm)*4 + i][(qn)*2 + n] = __builtin_amdgcn_mfma_f32_16x16x32_bf16( \
              aF[i][ks], b_[n][ks], acc[(qm)*4 + i][(qn)*2 + n], 0, 0, 0);     \
    __builtin_amdgcn_s_setprio(0);                                             \
    __builtin_amdgcn_s_barrier();                                              \
  }

  STG_A(0, 0, 0);
  STG_B(0, 0, 0);
  STG_A(0, 1, 0);
  STG_B(0, 1, 0);
  STG_B(1, 0, 1);
  asm volatile("s_waitcnt vmcnt(2)" ::: "memory");
  __builtin_amdgcn_s_barrier();

#pragma unroll 1
  for (int j = 0; j < 8; ++j) {
    const int t1 = 2 * j + 1;
    const int t2 = 2 * j + 2;
    const int t3 = 2 * j + 3;
    DO_PHASE(0, 0, 0, 1, { STG_A(1, 0, t1); }, 0);
    DO_PHASE(0, 1, 0, 0, { STG_A(1, 1, t1); }, 0);
    DO_PHASE(1, 0, 0, 1, { STG_B(1, 1, t1); }, 0);
    DO_PHASE(1, 1, 0, 0, { if (t2 < 16) STG_B(0, 0, t2); }, 1);
    DO_PHASE(0, 0, 1, 1, { if (t2 < 16) STG_A(0, 0, t2); }, 0);
    DO_PHASE(0, 1, 1, 0, { if (t2 < 16) STG_A(0, 1, t2); }, 0);
    DO_PHASE(1, 0, 1, 1, { if (t2 < 16) STG_B(0, 1, t2); }, 0);
    DO_PHASE(1, 1, 1, 0, { if (t3 < 16) STG_B(1, 0, t3); }, 1);
  }

  const int orow0 = bm * 256 + wr * 128 + lg * 4;
  const int ocol0 = bn * 256 + wc * 64 + l15;
#pragma unroll
  for (int mi = 0; mi < 8; ++mi)
#pragma unroll
    for (int ni = 0; ni < 4; ++ni)
#pragma unroll
      for (int r = 0; r < 4; ++r)
        C[(size_t)(orow0 + mi * 16 + r) * NQKV + ocol0 + ni * 16] = f2bf(acc[mi][ni][r]);
#undef STG_A
#undef STG_B
#undef DO_PHASE
}

// ---------------------------------------------------------------------------
// Fallback fp32-input GEMM for small ws (round-1 verified).
// ---------------------------------------------------------------------------
__global__ __launch_bounds__(256) void qkv_gemm(const float* __restrict__ X,
                                                const float* __restrict__ W,
                                                unsigned short* __restrict__ QKV) {
  __shared__ unsigned short sA[128 * 32];
  __shared__ unsigned short sB[128 * 32];
  const int tid  = threadIdx.x;
  const int lane = tid & 63;
  const int wave = tid >> 6;
  const int wr = wave >> 1, wc = wave & 1;
  const int row0 = blockIdx.x * 128;
  const int col0 = blockIdx.y * 128;

  f32x4 acc[4][4];
#pragma unroll
  for (int i = 0; i < 4; ++i)
#pragma unroll
    for (int j = 0; j < 4; ++j)
#pragma unroll
      for (int r = 0; r < 4; ++r) acc[i][j][r] = 0.f;

  const int srow = tid >> 1;
  const int scol = (tid & 1) * 16;
  union U16 { unsigned short s[8]; uint4 v; };

#pragma unroll 1
  for (int k0 = 0; k0 < D_MODEL; k0 += 32) {
    {
      const float* ga = X + (size_t)(row0 + srow) * D_MODEL + k0 + scol;
      const float* gb = W + (size_t)(col0 + srow) * D_MODEL + k0 + scol;
      float va[16], vb[16];
#pragma unroll
      for (int i = 0; i < 4; ++i) {
        float4 t = ((const float4*)ga)[i];
        va[4*i+0] = t.x; va[4*i+1] = t.y; va[4*i+2] = t.z; va[4*i+3] = t.w;
        float4 u = ((const float4*)gb)[i];
        vb[4*i+0] = u.x; vb[4*i+1] = u.y; vb[4*i+2] = u.z; vb[4*i+3] = u.w;
      }
      U16 ua0, ua1, ub0, ub1;
#pragma unroll
      for (int e = 0; e < 8; ++e) {
        ua0.s[e] = f2bf(va[e]);   ua1.s[e] = f2bf(va[8 + e]);
        ub0.s[e] = f2bf(vb[e]);   ub1.s[e] = f2bf(vb[8 + e]);
      }
      *(uint4*)&sA[srow * 32 + scol + 0] = ua0.v;
      *(uint4*)&sA[srow * 32 + scol + 8] = ua1.v;
      *(uint4*)&sB[srow * 32 + scol + 0] = ub0.v;
      *(uint4*)&sB[srow * 32 + scol + 8] = ub1.v;
    }
    __syncthreads();

    const int lrow = lane & 15;
    const int lk   = (lane >> 4) * 8;
    bf16x8 av[4], bv[4];
#pragma unroll
    for (int i = 0; i < 4; ++i)
      av[i] = *(const bf16x8*)&sA[(wr * 64 + i * 16 + lrow) * 32 + lk];
#pragma unroll
    for (int j = 0; j < 4; ++j)
      bv[j] = *(const bf16x8*)&sB[(wc * 64 + j * 16 + lrow) * 32 + lk];
#pragma unroll
    for (int i = 0; i < 4; ++i)
#pragma unroll
      for (int j = 0; j < 4; ++j)
        acc[i][j] = __builtin_amdgcn_mfma_f32_16x16x32_bf16(av[i], bv[j], acc[i][j], 0, 0, 0);
    __syncthreads();
  }

  const int orow = row0 + wr * 64 + (lane >> 4) * 4;
  const int ocol = col0 + wc * 64 + (lane & 15);
#pragma unroll
  for (int i = 0; i < 4; ++i)
#pragma unroll
    for (int j = 0; j < 4; ++j)
#pragma unroll
      for (int r = 0; r < 4; ++r)
        QKV[(size_t)(orow + i * 16 + r) * NQKV + ocol + j * 16] = f2bf(acc[i][j][r]);
}

// ---------------------------------------------------------------------------
// Causal flash attention attn10 = attn9 with the per-substep cross-half
// reductions removed: lane-local max + full-wave defer ballot (xchg32 only
// in the rare rescale branch); lane-local l merged by ONE xchg32 in the
// epilogue. PV depends only on exp2 outputs now.
// ---------------------------------------------------------------------------
__global__ __launch_bounds__(256, 2) void attn10(const unsigned short* __restrict__ QKV,
                                                 float* __restrict__ Out) {
  __shared__ unsigned short sK [2][2][64 * 64];
  __shared__ unsigned short sVt[2][2][64 * 64];

  const int tid  = threadIdx.x;
  const int lane = tid & 63;
  const int wave = tid >> 6;
  const int l31  = lane & 31;
  const int hi   = lane >> 5;

  const int x = blockIdx.x;
  int bh, u;
  if (x < 256) { bh = x & 31; u = x >> 5; }
  else         { const int x2 = x - 256; bh = x2 & 31; u = 15 - (x2 >> 5); }

  const int b = bh >> 4, h = bh & 15;
  const int q0w  = u * 128 + wave * 32;
  const int qcol = q0w + l31;

  const unsigned short* Qbase = QKV + (size_t)(b * TOKENS) * NQKV + h * HDIM;
  const unsigned short* Kbase = Qbase + D_MODEL;
  const unsigned short* Vbase = Kbase + D_MODEL;

  bf16x8 qf[4];
  {
    const unsigned short* qrow = Qbase + (size_t)qcol * NQKV + hi * 8;
    union { unsigned short us[8]; bf16x8 v; ushort4 q[2]; } t;
#pragma unroll
    for (int dk = 0; dk < 4; ++dk) {
      t.q[0] = ((const ushort4*)(qrow + dk * 16))[0];
      t.q[1] = ((const ushort4*)(qrow + dk * 16))[1];
#pragma unroll
      for (int e = 0; e < 8; ++e) t.us[e] = f2bf(bf2f(t.us[e]) * SCALE);
      qf[dk] = t.v;
    }
  }

  f32x16 o0, o1;
#pragma unroll
  for (int r = 0; r < 16; ++r) { o0[r] = 0.f; o1[r] = 0.f; }
  float m = -1e30f, ll = 0.f;    // ll is LANE-LOCAL (this lane's keys only)

  const int vk0 = (tid & 15) * 4;
  const int vd0 = (tid >> 4) * 4;
  ushort4 va0, va1, va2, va3, vb0, vb1, vb2, vb3;

  const int lane16 = lane * 16;

#define KGLOAD(kt, buf, s)                                                     \
  {                                                                            \
    _Pragma("unroll")                                                          \
    for (int g = 0; g < 2; ++g) {                                              \
      const int base = g * 4096 + wave * 1024;                                 \
      const int d = base + lane16;                                             \
      const int row = d >> 7;                                                  \
      const int grow = (row & 51) | ((row & 4) << 1) | ((row & 8) >> 1);       \
      const int cb = (d & 127) ^ ((row & 7) << 4);                             \
      GLOAD16(Kbase + (size_t)((kt) * 64 + grow) * NQKV + (cb >> 1),           \
              (char*)&sK[buf][s][0] + base + lane16);                          \
    }                                                                          \
  }

#define VLOAD2(pp)                                                             \
  {                                                                            \
    const unsigned short* vsA = Vbase + (size_t)((2*(pp)) * 64 + vk0) * NQKV + vd0;   \
    va0 = *(const ushort4*)(vsA);                                              \
    va1 = *(const ushort4*)(vsA + NQKV);                                       \
    va2 = *(const ushort4*)(vsA + 2 * NQKV);                                   \
    va3 = *(const ushort4*)(vsA + 3 * NQKV);                                   \
    const unsigned short* vsB = Vbase + (size_t)((2*(pp)+1) * 64 + vk0) * NQKV + vd0; \
    vb0 = *(const ushort4*)(vsB);                                              \
    vb1 = *(const ushort4*)(vsB + NQKV);                                       \
    vb2 = *(const ushort4*)(vsB + 2 * NQKV);                                   \
    vb3 = *(const ushort4*)(vsB + 3 * NQKV);                                   \
  }

#define VWRITE1(buf, s, t0, t1, t2, t3)                                        \
  {                                                                            \
    ushort4 c0, c1, c2, c3;                                                    \
    c0.x = t0.x; c0.y = t1.x; c0.z = t2.x; c0.w = t3.x;                        \
    c1.x = t0.y; c1.y = t1.y; c1.z = t2.y; c1.w = t3.y;                        \
    c2.x = t0.z; c2.y = t1.z; c2.z = t2.z; c2.w = t3.z;                        \
    c3.x = t0.w; c3.y = t1.w; c3.z = t2.w; c3.w = t3.w;                        \
    char* dV = (char*)&sVt[buf][s][0];                                         \
    _Pragma("unroll")                                                          \
    for (int e = 0; e < 4; ++e) {                                              \
      const int dim = vd0 + e;                                                 \
      const int o2 = (dim * 128 + vk0 * 2) ^ ((dim & 7) << 4);                 \
      ushort4 cc = (e == 0) ? c0 : (e == 1) ? c1 : (e == 2) ? c2 : c3;         \
      *(ushort4*)(dV + o2) = cc;                                               \
    }                                                                          \
  }

#define QKT(cK, rowbase, st)                                                   \
  {                                                                            \
    _Pragma("unroll")                                                          \
    for (int dk = 0; dk < 4; ++dk) {                                           \
      const int row = (rowbase);                                               \
      bf16x8 kf = *(const bf16x8*)((cK) + ((row * 128 + hi * 16 + dk * 32) ^ ((row & 7) << 4))); \
      st = __builtin_amdgcn_mfma_f32_32x32x16_bf16(kf, qf[dk], st, 0, 0, 0);   \
    }                                                                          \
  }

#define PV4(cV, bpX, bpY, koff)                                                \
  {                                                                            \
    const int r0 = l31, r1 = l31 + 32;                                         \
    bf16x8 vf;                                                                 \
    vf = *(const bf16x8*)((cV) + ((r0 * 128 + hi * 16 + (koff)) ^ ((r0 & 7) << 4)));      \
    o0 = __builtin_amdgcn_mfma_f32_32x32x16_bf16(vf, bpX, o0, 0, 0, 0);        \
    vf = *(const bf16x8*)((cV) + ((r1 * 128 + hi * 16 + (koff)) ^ ((r1 & 7) << 4)));      \
    o1 = __builtin_amdgcn_mfma_f32_32x32x16_bf16(vf, bpX, o1, 0, 0, 0);        \
    vf = *(const bf16x8*)((cV) + ((r0 * 128 + hi * 16 + (koff) + 32) ^ ((r0 & 7) << 4))); \
    o0 = __builtin_amdgcn_mfma_f32_32x32x16_bf16(vf, bpY, o0, 0, 0, 0);        \
    vf = *(const bf16x8*)((cV) + ((r1 * 128 + hi * 16 + (koff) + 32) ^ ((r1 & 7) << 4))); \
    o1 = __builtin_amdgcn_mfma_f32_32x32x16_bf16(vf, bpY, o1, 0, 0, 0);        \
  }

// lane-local max + wave ballot; xchg32 only in the rare rescale branch
#define MUPDATE(mx)                                                            \
  {                                                                            \
    if (!__all((mx) - m <= 8.f)) {                                             \
      float mw = fmaxf((mx), xchg32(mx));                                      \
      const float mnew = fmaxf(m, mw);                                         \
      const float corr = exp2f(m - mnew);                                      \
      m = mnew;                                                                \
      ll *= corr;                                                              \
      _Pragma("unroll")                                                        \
      for (int r = 0; r < 16; ++r) { o0[r] *= corr; o1[r] *= corr; }           \
    }                                                                          \
  }

  KGLOAD(0, 0, 0);
  KGLOAD(1, 0, 1);
  VLOAD2(0);
  VWRITE1(0, 0, va0, va1, va2, va3);
  VWRITE1(0, 1, vb0, vb1, vb2, vb3);
  __syncthreads();

#pragma unroll 1
  for (int p = 0; p < u; ++p) {
    const int cur = p & 1;
    KGLOAD(2 * (p + 1),     cur ^ 1, 0);
    KGLOAD(2 * (p + 1) + 1, cur ^ 1, 1);
    VLOAD2(p + 1);

    const char* cKA = (const char*)&sK[cur][0][0];
    const char* cKB = (const char*)&sK[cur][1][0];
    const char* cVA = (const char*)&sVt[cur][0][0];
    const char* cVB = (const char*)&sVt[cur][1][0];

    f32x16 sA0, sA1, sB0, sB1;
#pragma unroll
    for (int r = 0; r < 16; ++r) { sA0[r] = 0.f; sA1[r] = 0.f; sB0[r] = 0.f; sB1[r] = 0.f; }

    QKT(cKA, l31,      sA0);
    QKT(cKA, l31 + 32, sA1);
    QKT(cKB, l31,      sB0);
    QKT(cKB, l31 + 32, sB1);

    {
      float mx = max32t(sA0, sA1);
      MUPDATE(mx);
      float pA0[16], pA1[16];
#pragma unroll
      for (int r = 0; r < 16; ++r) { pA0[r] = exp2f(sA0[r] - m); pA1[r] = exp2f(sA1[r] - m); }
      ll += sum32t(pA0, pA1);
      bf16x8 a0 = pfrag8(&pA0[0]), a1 = pfrag8(&pA0[8]);
      bf16x8 a2 = pfrag8(&pA1[0]), a3 = pfrag8(&pA1[8]);
      PV4(cVA, a0, a1, 0);
      PV4(cVA, a2, a3, 64);
    }

    {
      float mx = max32t(sB0, sB1);
      MUPDATE(mx);
      float pB0[16], pB1[16];
#pragma unroll
      for (int r = 0; r < 16; ++r) { pB0[r] = exp2f(sB0[r] - m); pB1[r] = exp2f(sB1[r] - m); }
      ll += sum32t(pB0, pB1);
      bf16x8 b0 = pfrag8(&pB0[0]), b1 = pfrag8(&pB0[8]);
      bf16x8 b2 = pfrag8(&pB1[0]), b3 = pfrag8(&pB1[8]);
      PV4(cVB, b0, b1, 0);
      PV4(cVB, b2, b3, 64);
    }

    VWRITE1(cur ^ 1, 0, va0, va1, va2, va3);
    VWRITE1(cur ^ 1, 1, vb0, vb1, vb2, vb3);
    __syncthreads();
  }

  {
    const int cur = u & 1;
    const char* cK[2] = { (const char*)&sK[cur][0][0], (const char*)&sK[cur][1][0] };
    const char* cV[2] = { (const char*)&sVt[cur][0][0], (const char*)&sVt[cur][1][0] };
    const int nsub = (wave >= 2) ? 2 : 1;
#pragma unroll 1
    for (int s = 0; s < nsub; ++s) {
      const int kbase = u * 128 + s * 64;
      const bool diag  = (wave >= 2) ? (s == 1) : true;
      const bool do_hi = diag ? ((wave & 1) == 1) : true;

      f32x16 st0, st1;
#pragma unroll
      for (int r = 0; r < 16; ++r) { st0[r] = 0.f; st1[r] = 0.f; }

      QKT(cK[s], l31, st0);
      if (do_hi) QKT(cK[s], l31 + 32, st1);

      if (diag) {
#pragma unroll
        for (int r = 0; r < 16; ++r) {
          const int key0 = kbase + (r & 7) + ((r & 8) << 1) + 8 * hi;
          if (key0 > qcol) st0[r] = -1e30f;
          if (do_hi && key0 + 32 > qcol) st1[r] = -1e30f;
        }
      }

      float mx = do_hi ? max32t(st0, st1) : max32t(st0, st0);
      MUPDATE(mx);

      float p0[16], p1[16];
#pragma unroll
      for (int r = 0; r < 16; ++r) p0[r] = exp2f(st0[r] - m);
      if (do_hi) {
#pragma unroll
        for (int r = 0; r < 16; ++r) p1[r] = exp2f(st1[r] - m);
        ll += sum32t(p0, p1);
      } else {
        float z[16];
#pragma unroll
        for (int r = 0; r < 16; ++r) z[r] = 0.f;
        ll += sum32t(p0, z);
      }

      bf16x8 c0 = pfrag8(&p0[0]), c1 = pfrag8(&p0[8]);
      PV4(cV[s], c0, c1, 0);
      if (do_hi) {
        bf16x8 c2 = pfrag8(&p1[0]), c3 = pfrag8(&p1[8]);
        PV4(cV[s], c2, c3, 64);
      }
    }
  }

  {
    const float lfull = ll + xchg32(ll);   // merge the two key-halves once
    const float inv = 1.f / lfull;
    float* orow = Out + (size_t)(b * TOKENS + qcol) * D_MODEL + h * HDIM;
#pragma unroll
    for (int g = 0; g < 4; ++g) {
      float4 w0, w1;
      w0.x = o0[4*g+0] * inv; w0.y = o0[4*g+1] * inv;
      w0.z = o0[4*g+2] * inv; w0.w = o0[4*g+3] * inv;
      w1.x = o1[4*g+0] * inv; w1.y = o1[4*g+1] * inv;
      w1.z = o1[4*g+2] * inv; w1.w = o1[4*g+3] * inv;
      *(float4*)(orow + 8 * g + 4 * hi)      = w0;
      *(float4*)(orow + 8 * g + 4 * hi + 32) = w1;
    }
  }
#undef KGLOAD
#undef VLOAD2
#undef VWRITE1
#undef QKT
#undef PV4
#undef MUPDATE
}

extern "C" void kernel_launch(void* const* d_in, const int* in_sizes, int n_in,
                              void* d_out, int out_size, void* d_ws, size_t ws_size,
                              hipStream_t stream) {
  const float* X = (const float*)d_in[0];
  const float* W = (const float*)d_in[1];
  float* Out = (float*)d_out;
  unsigned short* QKV = (unsigned short*)d_ws;

  const size_t QKV_E = (size_t)MROWS * NQKV;
  const size_t XB_E  = (size_t)MROWS * D_MODEL;
  const size_t WB_E  = (size_t)NQKV * D_MODEL;
  const size_t need_bf16 = (QKV_E + XB_E + WB_E) * 2;

  if (ws_size >= need_bf16) {
    unsigned short* Xb = QKV + QKV_E;
    unsigned short* Wb = Xb + XB_E;
    cvt_bf16<<<(XB_E + WB_E) / (256 * 8), 256, 0, stream>>>(X, W, Xb, Wb);
    gemm8<<<dim3(MROWS / 256, NQKV / 256), 512, 0, stream>>>(Xb, Wb, QKV);
  } else {
    qkv_gemm<<<dim3(MROWS / 128, NQKV / 128), 256, 0, stream>>>(X, W, QKV);
  }

  attn10<<<512, 256, 0, stream>>>(QKV, Out);
}